// Round 14
// baseline (231.517 us; speedup 1.0000x reference)
//
#include <hip/hip_runtime.h>

using f16x8 = __attribute__((ext_vector_type(8))) _Float16;
using f32x4 = __attribute__((ext_vector_type(4))) float;
using u16x8 = __attribute__((ext_vector_type(8))) unsigned short;

constexpr int B = 64, I = 700, H = 2048, O = 20, T = 100;
constexpr int NKT0 = 22;        // K-tiles layer 0 (704 = 22*32)  (even)
constexpr int NKT1 = 64;        // K-tiles layer 1 (2048 = 64*32) (even)
// A image (global only now): [4 g][128 rows (64 hi + 64 lo)][8 f16] per kt
// B tile (LDS-staged):       [4 g][112 rows (t)][8 f16] per b per kt
constexpr int A_TILE = 4096;    // ushorts
constexpr int B_TILE = 3584;    // ushorts
constexpr int DBUF = 14336;     // bytes: one LDS buffer = 2 bb x 448 chunks x 16
constexpr int SMEM_BYTES = 51712;   // scan overlay 2*64*101*4 (> 2*DBUF = 28672)

#define GLOAD16(gp, lp) __builtin_amdgcn_global_load_lds( \
    (const __attribute__((address_space(1))) unsigned int*)(const void*)(gp), \
    (__attribute__((address_space(3))) unsigned int*)(void*)(lp), 16, 0, 0)

// ---------------- pre-pass: W fp32 -> split-f16 A-tiles ----------------------
__global__ __launch_bounds__(256) void convert_w_tiled(
    const float* __restrict__ w, int K, int NKT, int total,
    unsigned short* __restrict__ dst)
{
    int idx = blockIdx.x * 256 + threadIdx.x;
    if (idx >= total) return;
    int c = idx & 511, img = idx >> 9;
    int h0blk = img / NKT, kt = img - h0blk * NKT;
    int g = c >> 7, row = c & 127;
    int sp = row >> 6, hr = row & 63;
    int kbase = kt * 32 + g * 8;
    const float* wrow = w + (size_t)(h0blk * 64 + hr) * K;
    u16x8 outv;
    #pragma unroll
    for (int j = 0; j < 8; ++j) {
        int k = kbase + j;
        float f = (k < K) ? wrow[k] : 0.f;
        _Float16 hi = (_Float16)f;
        _Float16 val = (sp == 0) ? hi : (_Float16)(f - (float)hi);
        outv[j] = *(unsigned short*)&val;
    }
    *(u16x8*)&dst[(size_t)idx * 8] = outv;
}

// ---------------- pre-pass: X fp32 [B][I][T] -> B-tiles ----------------------
__global__ __launch_bounds__(256) void transpose_x_tiled(
    const float* __restrict__ X, unsigned short* __restrict__ XT)
{
    __shared__ float xs[32][101];
    int kt = blockIdx.x, b = blockIdx.y;
    int c0 = kt * 32;
    const float* Xb = X + (size_t)b * I * T;
    for (int idx = threadIdx.x; idx < 32 * T; idx += 256) {
        int ci = idx / T, t = idx - (idx / T) * T;
        xs[ci][t] = (c0 + ci < I) ? Xb[(size_t)(c0 + ci) * T + t] : 0.f;
    }
    __syncthreads();
    unsigned short* dst = XT + ((size_t)b * NKT0 + kt) * B_TILE;
    for (int idx = threadIdx.x; idx < 448; idx += 256) {
        int g = idx / 112, r = idx - (idx / 112) * 112;
        u16x8 outv;
        #pragma unroll
        for (int j = 0; j < 8; ++j) {
            float f = (r < T) ? xs[g * 8 + j][r] : 0.f;
            _Float16 h = (_Float16)f;
            outv[j] = *(unsigned short*)&h;
        }
        *(u16x8*)&dst[(size_t)idx * 8] = outv;
    }
}

// ---------------- pre-pass: ro fp32 [O][H] -> ro A-tiles (per kt32) ----------
__global__ __launch_bounds__(128) void convert_ro_tiled(
    const float* __restrict__ ro, unsigned short* __restrict__ dst)
{
    int kt = blockIdx.x;              // 0..63
    int c = threadIdx.x;              // 0..127
    int g = c >> 5, row = c & 31;
    int k0 = kt * 32 + g * 8;
    u16x8 outv;
    #pragma unroll
    for (int j = 0; j < 8; ++j) {
        float f = (row < O) ? ro[(size_t)row * H + k0 + j] : 0.f;
        _Float16 hv = (_Float16)f;
        outv[j] = *(unsigned short*)&hv;
    }
    *(u16x8*)&dst[((size_t)kt * 128 + c) * 8] = outv;
}

// ------ fused MFMA GEMM: A global->reg ping-pong, B LDS-staged (BN=2) + scan --
__global__ __launch_bounds__(256, 3) void gemm_scan_mfma9(
    const unsigned short* __restrict__ WA,   // [32][NKT][A_TILE]
    const unsigned short* __restrict__ XB,   // [64][NKT][B_TILE]
    int NKT,
    float* __restrict__ S, float* __restrict__ V,
    unsigned short* __restrict__ sT)         // [64][NKT1][B_TILE] spike image out
{
    __shared__ __align__(16) char smem[SMEM_BYTES];
    const int tid = threadIdx.x;
    const int lane = tid & 63, wave = tid >> 6;
    const int lm = lane & 15, lg = lane >> 4;
    const int wr = wave >> 1, wc = wave & 1;
    const int NTW = 4 - wc;

    // XCD-aware decode: blocks with same b-pair land on same XCD
    int orig = blockIdx.x;                  // 0..1023
    int xcd = orig & 7, slot = orig >> 3;   // slot 0..127
    int bp = xcd * 4 + (slot & 3);          // b-pair 0..31
    int b0 = bp * 2;
    int h0blk = slot >> 2;                  // 0..31

    const unsigned short* WAblk = WA + (size_t)h0blk * NKT * A_TILE;
    const unsigned short* XBb0  = XB + (size_t)b0 * NKT * B_TILE;
    const unsigned short* XBb1  = XB + (size_t)(b0 + 1) * NKT * B_TILE;

    // A fragment u16 offsets within one kt-image (kt-invariant)
    int au16[2][2];
    #pragma unroll
    for (int sp = 0; sp < 2; ++sp)
        #pragma unroll
        for (int ar = 0; ar < 2; ++ar) {
            int row = sp * 64 + wr * 32 + ar * 16 + lm;
            au16[sp][ar] = lg * 1024 + row * 8;
        }
    // B fragment byte offsets within one LDS buffer
    int boff[2][4];
    #pragma unroll
    for (int bb = 0; bb < 2; ++bb)
        #pragma unroll
        for (int nt = 0; nt < 4; ++nt) {
            int row = wc * 64 + nt * 16 + lm;
            boff[bb][nt] = bb * 7168 + lg * 1792 + row * 16;
        }

    f32x4 acc[2][2][4];   // [b-batch][ar][nt]
    #pragma unroll
    for (int bb = 0; bb < 2; ++bb)
        #pragma unroll
        for (int ar = 0; ar < 2; ++ar)
            #pragma unroll
            for (int nt = 0; nt < 4; ++nt)
                acc[bb][ar][nt] = (f32x4){0.f, 0.f, 0.f, 0.f};

#define STAGE_B(kt_, lds_) do {                                                \
        _Pragma("unroll")                                                      \
        for (int j_ = 0; j_ < 4; ++j_) {                                       \
            int idx_ = tid + j_ * 256;                                         \
            if (idx_ < 896) {                                                  \
                const unsigned short* g_ = (idx_ < 448)                        \
                    ? XBb0 + (size_t)(kt_) * B_TILE + (size_t)idx_ * 8         \
                    : XBb1 + (size_t)(kt_) * B_TILE + (size_t)(idx_ - 448) * 8;\
                GLOAD16(g_, (lds_) + idx_ * 16);                               \
            }                                                                  \
        }                                                                      \
    } while (0)

#define LOADA(dst_, kt_) do {                                                  \
        const unsigned short* ap_ = WAblk + (size_t)(kt_) * A_TILE;            \
        _Pragma("unroll")                                                      \
        for (int sp_ = 0; sp_ < 2; ++sp_)                                      \
            _Pragma("unroll")                                                  \
            for (int ar_ = 0; ar_ < 2; ++ar_)                                  \
                dst_[sp_][ar_] = *(const f16x8*)&ap_[au16[sp_][ar_]];          \
    } while (0)

#define MFMA_PHASE(base_, a_) do {                                             \
        _Pragma("unroll")                                                      \
        for (int bb_ = 0; bb_ < 2; ++bb_) {                                    \
            f16x8 bf_[4];                                                      \
            _Pragma("unroll")                                                  \
            for (int nt_ = 0; nt_ < 4; ++nt_)                                  \
                if (nt_ < NTW)                                                 \
                    bf_[nt_] = *(const f16x8*)((base_) + boff[bb_][nt_]);      \
            _Pragma("unroll")                                                  \
            for (int nt_ = 0; nt_ < 4; ++nt_) {                                \
                if (nt_ >= NTW) continue;                                      \
                acc[bb_][0][nt_] = __builtin_amdgcn_mfma_f32_16x16x32_f16(     \
                    a_[0][0], bf_[nt_], acc[bb_][0][nt_], 0, 0, 0);            \
                acc[bb_][0][nt_] = __builtin_amdgcn_mfma_f32_16x16x32_f16(     \
                    a_[1][0], bf_[nt_], acc[bb_][0][nt_], 0, 0, 0);            \
                acc[bb_][1][nt_] = __builtin_amdgcn_mfma_f32_16x16x32_f16(     \
                    a_[0][1], bf_[nt_], acc[bb_][1][nt_], 0, 0, 0);            \
                acc[bb_][1][nt_] = __builtin_amdgcn_mfma_f32_16x16x32_f16(     \
                    a_[1][1], bf_[nt_], acc[bb_][1][nt_], 0, 0, 0);            \
            }                                                                  \
        }                                                                      \
    } while (0)

    f16x8 aA[2][2], aB[2][2];   // ping-pong A register sets

    // prologue: stage B(0) into buf0; load A(0) into aA
    STAGE_B(0, smem);
    LOADA(aA, 0);
    __syncthreads();

    for (int kt = 0; kt < NKT; kt += 2) {
        // even phase: compute kt (buf0, aA); prefetch kt+1 (buf1, aB)
        STAGE_B(kt + 1, smem + DBUF);
        LOADA(aB, kt + 1);
        MFMA_PHASE(smem, aA);
        __syncthreads();
        // odd phase: compute kt+1 (buf1, aB); prefetch kt+2 (buf0, aA)
        if (kt + 2 < NKT) {
            STAGE_B(kt + 2, smem);
            LOADA(aA, kt + 2);
        }
        MFMA_PHASE(smem + DBUF, aB);
        __syncthreads();
    }
#undef STAGE_B
#undef LOADA
#undef MFMA_PHASE

    // ---- scan phase: reuse LDS ----
    float* zt = (float*)smem;                      // [2][64][101] f32 = 51712 B
    #pragma unroll
    for (int bb = 0; bb < 2; ++bb)
        #pragma unroll
        for (int ar = 0; ar < 2; ++ar)
            #pragma unroll
            for (int nt = 0; nt < 4; ++nt) {
                if (nt >= NTW) continue;
                int t = wc * 64 + nt * 16 + lm;
                if (t < T) {
                    #pragma unroll
                    for (int r = 0; r < 4; ++r) {
                        int h = wr * 32 + ar * 16 + lg * 4 + r;
                        zt[(bb * 64 + h) * 101 + t] = acc[bb][ar][nt][r];
                    }
                }
            }
    __syncthreads();

    if (tid < 128) {   // 128 LIF chains: [bb=tid>>6][h=tid&63]
        float cur2 = 0.f, v = 0.f;
        for (int t = 0; t < T; ++t) {
            cur2 = fmaf(0.75f, cur2, zt[tid * 101 + t]);
            v    = fmaf(0.97f, v, cur2);
            float vpre = v;
            zt[tid * 101 + t] = vpre;
            v = (vpre >= 1.25f) ? 0.f : vpre;   // hard reset
        }
    }
    __syncthreads();

    // ---- global write-out S, V (spike recomputed from pre-reset voltage) ----
    #pragma unroll
    for (int bb = 0; bb < 2; ++bb) {
        size_t gbase = ((size_t)(b0 + bb) * H + h0blk * 64) * T;
        const float* ztb = zt + bb * 6464;
        for (int idx = tid; idx < 1600; idx += 256) {
            int h = idx / 25, q = idx - (idx / 25) * 25;
            int t0 = q * 4;
            f32x4 sv, vv;
            #pragma unroll
            for (int i = 0; i < 4; ++i) {
                float vpre = ztb[h * 101 + t0 + i];
                vv[i] = vpre;
                sv[i] = (vpre >= 1.25f) ? 1.f : 0.f;
            }
            *(f32x4*)&S[gbase + (size_t)h * 100 + t0] = sv;
            *(f32x4*)&V[gbase + (size_t)h * 100 + t0] = vv;
        }
    }
    // ---- spike image: 2 b's x 2 sub-tiles (32 channels each) ----
    for (int idx = tid; idx < 1792; idx += 256) {
        int bb = idx / 896, c2 = idx - bb * 896;
        int sub = c2 / 448, c = c2 - sub * 448;
        int g = c / 112, r = c - (c / 112) * 112;
        int ch0 = sub * 32 + g * 8;
        const float* ztb = zt + bb * 6464;
        u16x8 outv;
        #pragma unroll
        for (int j = 0; j < 8; ++j) {
            bool sp = (r < T) && (ztb[(ch0 + j) * 101 + r] >= 1.25f);
            outv[j] = sp ? 0x3C00 : 0;
        }
        unsigned short* dstb = sT + ((size_t)(b0 + bb) * NKT1 + h0blk * 2 + sub) * B_TILE;
        *(u16x8*)&dstb[(size_t)c * 8] = outv;
    }
}

// ------ readout from images: R[l][b][o][t] = sum_h ro[o][h]*s[h][t], MFMA ------
__global__ __launch_bounds__(256) void readout_img(
    const unsigned short* __restrict__ r0img,  // [64][128 chunks][8]
    const unsigned short* __restrict__ r1img,
    const unsigned short* __restrict__ s0img,  // [64 b][64 kt][B_TILE]
    const unsigned short* __restrict__ s1img,
    float* __restrict__ R)                     // [2][B][O][T]
{
    __shared__ float red[4][2][7][4][64];      // 57344 B
    const int bid = blockIdx.x;
    const int l = bid >> 6, b = bid & 63;
    const unsigned short* ro = l ? r1img : r0img;
    const unsigned short* im = (l ? s1img : s0img) + (size_t)b * NKT1 * B_TILE;
    const int tid = threadIdx.x, lane = tid & 63, wave = tid >> 6;
    const int lm = lane & 15, lg = lane >> 4;

    f32x4 acc[2][7];
    #pragma unroll
    for (int ar = 0; ar < 2; ++ar)
        #pragma unroll
        for (int nt = 0; nt < 7; ++nt)
            acc[ar][nt] = (f32x4){0.f, 0.f, 0.f, 0.f};

    for (int kt = wave; kt < NKT1; kt += 4) {
        const unsigned short* A  = ro + (size_t)kt * 1024;
        const unsigned short* Bp = im + (size_t)kt * B_TILE;
        f16x8 a[2];
        #pragma unroll
        for (int ar = 0; ar < 2; ++ar) {
            int row = ar * 16 + lm;
            a[ar] = *(const f16x8*)&A[lg * 256 + row * 8];
        }
        #pragma unroll
        for (int nt = 0; nt < 7; ++nt) {
            int row = nt * 16 + lm;
            f16x8 bb = *(const f16x8*)&Bp[lg * 896 + row * 8];
            #pragma unroll
            for (int ar = 0; ar < 2; ++ar)
                acc[ar][nt] = __builtin_amdgcn_mfma_f32_16x16x32_f16(
                    a[ar], bb, acc[ar][nt], 0, 0, 0);
        }
    }
    #pragma unroll
    for (int ar = 0; ar < 2; ++ar)
        #pragma unroll
        for (int nt = 0; nt < 7; ++nt)
            #pragma unroll
            for (int r = 0; r < 4; ++r)
                red[wave][ar][nt][r][lane] = acc[ar][nt][r];
    __syncthreads();

    for (int idx = tid; idx < 3584; idx += 256) {
        int ln = idx & 63;
        int rest = idx >> 6;                 // 0..55
        int rg = rest & 3;
        int rest2 = rest >> 2;               // 0..13
        int nt = rest2 % 7, ar = rest2 / 7;
        float s = red[0][ar][nt][rg][ln] + red[1][ar][nt][rg][ln]
                + red[2][ar][nt][rg][ln] + red[3][ar][nt][rg][ln];
        int o = ar * 16 + (ln >> 4) * 4 + rg;
        int t = nt * 16 + (ln & 15);
        if (o < O && t < T)
            R[(((size_t)l * B + b) * O + o) * T + t] = s;
    }
}

// ---------------- standalone readout (fallback path only) ----------------
__global__ __launch_bounds__(128) void readout_kernel(
    const float* __restrict__ ro0, const float* __restrict__ ro1,
    const float* __restrict__ Sall, float* __restrict__ R)
{
    int bid = blockIdx.x;
    int l = bid / (B * O);
    int rem = bid - l * (B * O);
    int b = rem / O, o = rem - (rem / O) * O;
    int t = threadIdx.x;
    if (t >= T) return;
    const float* ro = (l == 0 ? ro0 : ro1) + (size_t)o * H;
    const float* s  = Sall + (size_t)l * B * H * T + (size_t)b * H * T + t;
    float acc = 0.f;
    #pragma unroll 8
    for (int h = 0; h < H; ++h)
        acc = fmaf(ro[h], s[(size_t)h * T], acc);
    R[(size_t)l * B * O * T + (size_t)b * O * T + (size_t)o * T + t] = acc;
}

// ---------------- fallback fp32 path (round-1, known correct) ----------------
__global__ __launch_bounds__(256) void gemm_scan_f32(
    const float* __restrict__ W, const float* __restrict__ X,
    int K, long xbs, float* __restrict__ S, float* __restrict__ V)
{
    __shared__ float fxs[16][112];
    __shared__ float fwl[64][16];
    __shared__ float fzt[64][101];
    __shared__ float fst[64][101];
    const int tid = threadIdx.x;
    const int tx = tid & 15, ty = tid >> 4;
    const int b = blockIdx.y, h0 = blockIdx.x * 64;
    const float* Xb = X + (long)b * xbs;
    float acc[4][7];
    #pragma unroll
    for (int k = 0; k < 4; ++k)
        #pragma unroll
        for (int j = 0; j < 7; ++j) acc[k][j] = 0.f;
    for (int cc = 0; cc < K; cc += 16) {
        for (int idx = tid; idx < 16 * 112; idx += 256) {
            int c = idx / 112, t = idx - c * 112;
            float v = 0.f;
            if (t < T && cc + c < K) v = Xb[(long)(cc + c) * T + t];
            fxs[c][t] = v;
        }
        for (int idx = tid; idx < 64 * 16; idx += 256) {
            int h = idx >> 4, c = idx & 15;
            float v = 0.f;
            if (cc + c < K) v = W[(long)(h0 + h) * K + cc + c];
            fwl[h][c] = v;
        }
        __syncthreads();
        #pragma unroll
        for (int c = 0; c < 16; ++c) {
            float wv[4], xv[7];
            #pragma unroll
            for (int k = 0; k < 4; ++k) wv[k] = fwl[ty + 16 * k][c];
            #pragma unroll
            for (int j = 0; j < 7; ++j) xv[j] = fxs[c][tx + 16 * j];
            #pragma unroll
            for (int k = 0; k < 4; ++k)
                #pragma unroll
                for (int j = 0; j < 7; ++j)
                    acc[k][j] = fmaf(wv[k], xv[j], acc[k][j]);
        }
        __syncthreads();
    }
    #pragma unroll
    for (int k = 0; k < 4; ++k)
        #pragma unroll
        for (int j = 0; j < 7; ++j) {
            int t = tx + 16 * j;
            if (t < T) fzt[ty + 16 * k][t] = acc[k][j];
        }
    __syncthreads();
    if (tid < 64) {
        float cur = 0.f, v = 0.f;
        for (int t = 0; t < T; ++t) {
            cur = fmaf(0.75f, cur, fzt[tid][t]);
            v = fmaf(0.97f, v, cur);
            float s = (v >= 1.25f) ? 1.f : 0.f;
            fst[tid][t] = s;
            fzt[tid][t] = v;
            v *= (1.f - s);
        }
    }
    __syncthreads();
    long base = (long)b * H * T + (long)h0 * T;
    for (int idx = tid; idx < 64 * T; idx += 256) {
        int h = idx / T, t = idx - (idx / T) * T;
        S[base + idx] = fst[h][t];
        V[base + idx] = fzt[h][t];
    }
}

extern "C" void kernel_launch(void* const* d_in, const int* in_sizes, int n_in,
                              void* d_out, int out_size, void* d_ws, size_t ws_size,
                              hipStream_t stream) {
    const float* spike = (const float*)d_in[0];
    const float* w0    = (const float*)d_in[1];
    const float* w1    = (const float*)d_in[2];
    const float* ro0   = (const float*)d_in[3];
    const float* ro1   = (const float*)d_in[4];

    float* out = (float*)d_out;
    float* S = out;
    float* R = out + 2L * B * H * T;
    float* V = out + 2L * B * H * T + 2L * B * O * T;

    const size_t nW0 = (size_t)32 * NKT0 * A_TILE;
    const size_t nW1 = (size_t)32 * NKT1 * A_TILE;
    const size_t nX0 = (size_t)B * NKT0 * B_TILE + 512;
    const size_t nS  = (size_t)B * NKT1 * B_TILE + 512;   // per-layer spike image
    const size_t nRO = (size_t)NKT1 * 1024;               // per-layer ro image
    const size_t need = (nW0 + nW1 + nX0 + 2 * nS + 2 * nRO) * sizeof(unsigned short);

    if (ws_size >= need) {
        unsigned short* p = (unsigned short*)d_ws;
        unsigned short* w0img = p; p += nW0;
        unsigned short* w1img = p; p += nW1;
        unsigned short* x0img = p; p += nX0;
        unsigned short* s0img = p; p += nS;
        unsigned short* s1img = p; p += nS;
        unsigned short* r0img = p; p += nRO;
        unsigned short* r1img = p; p += nRO;

        int t0 = 32 * NKT0 * 512, t1 = 32 * NKT1 * 512;
        convert_w_tiled<<<(t0 + 255) / 256, 256, 0, stream>>>(w0, I, NKT0, t0, w0img);
        convert_w_tiled<<<(t1 + 255) / 256, 256, 0, stream>>>(w1, H, NKT1, t1, w1img);
        transpose_x_tiled<<<dim3(NKT0, B), 256, 0, stream>>>(spike, x0img);
        convert_ro_tiled<<<NKT1, 128, 0, stream>>>(ro0, r0img);
        convert_ro_tiled<<<NKT1, 128, 0, stream>>>(ro1, r1img);

        gemm_scan_mfma9<<<1024, 256, 0, stream>>>(w0img, x0img, NKT0, S, V, s0img);
        gemm_scan_mfma9<<<1024, 256, 0, stream>>>(w1img, s0img, NKT1,
                                                  S + (size_t)B * H * T,
                                                  V + (size_t)B * H * T, s1img);
        readout_img<<<128, 256, 0, stream>>>(r0img, r1img, s0img, s1img, R);
    } else {
        dim3 grid(H / 64, B);
        gemm_scan_f32<<<grid, 256, 0, stream>>>(w0, spike, I, (long)I * T, S, V);
        gemm_scan_f32<<<grid, 256, 0, stream>>>(w1, S, H, (long)H * T,
                                                S + (long)B * H * T, V + (long)B * H * T);
        readout_kernel<<<2 * B * O, 128, 0, stream>>>(ro0, ro1, S, R);
    }
}

// Round 15
// 216.757 us; speedup vs baseline: 1.0681x; 1.0681x over previous
//
#include <hip/hip_runtime.h>

using f16x8 = __attribute__((ext_vector_type(8))) _Float16;
using f32x4 = __attribute__((ext_vector_type(4))) float;
using u16x8 = __attribute__((ext_vector_type(8))) unsigned short;

constexpr int B = 64, I = 700, H = 2048, O = 20, T = 100;
constexpr int NKT0 = 22;        // K-tiles layer 0 (704 = 22*32)
constexpr int NKT1 = 64;        // K-tiles layer 1 (2048 = 64*32)
// v2 tile layout (k-group-major, chunk-linear, bank-conflict-free):
//   A tile: [4 g][128 rows (64 hi + 64 lo)][8 f16]  = 512 chunks = 4096 ushorts
//   B tile: [4 g][112 rows (t)][8 f16]              = 448 chunks = 3584 ushorts
constexpr int A_TILE = 4096;    // ushorts
constexpr int B_TILE = 3584;    // ushorts
constexpr int TILE_BYTES = 15360;
constexpr int TOT_CHUNKS = 960; // 512 A + 448 B

// merged prepass block ranges
constexpr int PW0_BLKS = (32 * NKT0 * 512) / 256;   // 1408
constexpr int PW1_BLKS = (32 * NKT1 * 512) / 256;   // 4096
constexpr int PX_BLKS  = NKT0 * B;                  // 1408
constexpr int PRO_BLKS = NKT1;                      // 64 (both layers per block)
constexpr int PRE_BLKS = PW0_BLKS + PW1_BLKS + PX_BLKS + PRO_BLKS;

#define GLOAD16(gp, lp) __builtin_amdgcn_global_load_lds( \
    (const __attribute__((address_space(1))) unsigned int*)(const void*)(gp), \
    (__attribute__((address_space(3))) unsigned int*)(void*)(lp), 16, 0, 0)

// ---------------- merged pre-pass bodies ----------------
__device__ inline void conv_w_body(const float* __restrict__ w, int K, int NKT,
                                   int idx, unsigned short* __restrict__ dst)
{
    int c = idx & 511, img = idx >> 9;
    int h0blk = img / NKT, kt = img - h0blk * NKT;
    int g = c >> 7, row = c & 127;
    int sp = row >> 6, hr = row & 63;
    int kbase = kt * 32 + g * 8;
    const float* wrow = w + (size_t)(h0blk * 64 + hr) * K;
    u16x8 outv;
    #pragma unroll
    for (int j = 0; j < 8; ++j) {
        int k = kbase + j;
        float f = (k < K) ? wrow[k] : 0.f;
        _Float16 hi = (_Float16)f;
        _Float16 val = (sp == 0) ? hi : (_Float16)(f - (float)hi);
        outv[j] = *(unsigned short*)&val;
    }
    *(u16x8*)&dst[(size_t)idx * 8] = outv;
}

__global__ __launch_bounds__(256) void prepass_all(
    const float* __restrict__ spike,
    const float* __restrict__ w0, const float* __restrict__ w1,
    const float* __restrict__ ro0, const float* __restrict__ ro1,
    unsigned short* __restrict__ w0img, unsigned short* __restrict__ w1img,
    unsigned short* __restrict__ x0img,
    unsigned short* __restrict__ r0img, unsigned short* __restrict__ r1img)
{
    __shared__ float xs[32][101];
    int bid = blockIdx.x;
    if (bid < PW0_BLKS) {
        conv_w_body(w0, I, NKT0, bid * 256 + threadIdx.x, w0img);
    } else if (bid < PW0_BLKS + PW1_BLKS) {
        conv_w_body(w1, H, NKT1, (bid - PW0_BLKS) * 256 + threadIdx.x, w1img);
    } else if (bid < PW0_BLKS + PW1_BLKS + PX_BLKS) {
        // X transpose: fp32 [B][I][T] -> B-tiles (v2 layout)
        int q = bid - (PW0_BLKS + PW1_BLKS);
        int kt = q % NKT0, b = q / NKT0;
        int c0 = kt * 32;
        const float* Xb = spike + (size_t)b * I * T;
        for (int idx = threadIdx.x; idx < 32 * T; idx += 256) {
            int ci = idx / T, t = idx - (idx / T) * T;
            xs[ci][t] = (c0 + ci < I) ? Xb[(size_t)(c0 + ci) * T + t] : 0.f;
        }
        __syncthreads();
        unsigned short* dst = x0img + ((size_t)b * NKT0 + kt) * B_TILE;
        for (int idx = threadIdx.x; idx < 448; idx += 256) {
            int g = idx / 112, r = idx - (idx / 112) * 112;
            u16x8 outv;
            #pragma unroll
            for (int j = 0; j < 8; ++j) {
                float f = (r < T) ? xs[g * 8 + j][r] : 0.f;
                _Float16 h = (_Float16)f;
                outv[j] = *(unsigned short*)&h;
            }
            *(u16x8*)&dst[(size_t)idx * 8] = outv;
        }
    } else {
        // ro conversion, both layers: [O][H] -> per-kt32 A-tiles
        int kt = bid - (PW0_BLKS + PW1_BLKS + PX_BLKS);
        int l = threadIdx.x >> 7, c = threadIdx.x & 127;
        const float* ro = l ? ro1 : ro0;
        unsigned short* dst = l ? r1img : r0img;
        int g = c >> 5, row = c & 31;
        int k0 = kt * 32 + g * 8;
        u16x8 outv;
        #pragma unroll
        for (int j = 0; j < 8; ++j) {
            float f = (row < O) ? ro[(size_t)row * H + k0 + j] : 0.f;
            _Float16 hv = (_Float16)f;
            outv[j] = *(unsigned short*)&hv;
        }
        *(u16x8*)&dst[((size_t)kt * 128 + c) * 8] = outv;
    }
}

// ------ fused MFMA GEMM (BK=32, 2-phase gload_lds, 5 blocks/CU) + CUBA scan ----
// (round-9 champion, verbatim)
__global__ __launch_bounds__(256, 4) void gemm_scan_mfma4(
    const unsigned short* __restrict__ WA,   // [32][NKT][A_TILE]
    const unsigned short* __restrict__ XB,   // [64][NKT][B_TILE]
    int NKT,
    float* __restrict__ S, float* __restrict__ V,
    unsigned short* __restrict__ sT)         // [64][NKT1][B_TILE] spike image out
{
    __shared__ __align__(16) char smem[2 * TILE_BYTES];   // 30720 B (scan overlays)
    const int tid = threadIdx.x;
    const int lane = tid & 63, wave = tid >> 6;
    const int lm = lane & 15, lg = lane >> 4;
    const int wr = wave >> 1, wc = wave & 1;
    const int NTW = 4 - wc;

    // XCD-aware decode: blocks with same b land on same XCD
    int orig = blockIdx.x;
    int xcd = orig & 7, slot = orig >> 3;
    int b = xcd * 8 + (slot & 7);
    int h0blk = slot >> 3;

    const unsigned short* WAblk = WA + (size_t)h0blk * NKT * A_TILE;
    const unsigned short* XBb   = XB + (size_t)b * NKT * B_TILE;

    // fragment byte offsets within one buffer (kt-invariant)
    int aoff[2][2], boff[4];
    #pragma unroll
    for (int sp = 0; sp < 2; ++sp)
        #pragma unroll
        for (int ar = 0; ar < 2; ++ar) {
            int row = sp * 64 + wr * 32 + ar * 16 + lm;
            aoff[sp][ar] = lg * 2048 + row * 16;
        }
    #pragma unroll
    for (int nt = 0; nt < 4; ++nt) {
        int row = wc * 64 + nt * 16 + lm;
        boff[nt] = 8192 + lg * 1792 + row * 16;
    }

    f32x4 acc[2][4];
    #pragma unroll
    for (int ar = 0; ar < 2; ++ar)
        #pragma unroll
        for (int nt = 0; nt < 4; ++nt)
            acc[ar][nt] = (f32x4){0.f, 0.f, 0.f, 0.f};

    // prologue: stage kt=0 into buf 0
    {
        const unsigned short* wa = WAblk;
        const unsigned short* xb = XBb;
        #pragma unroll
        for (int j = 0; j < 4; ++j) {
            int idx = tid + j * 256;
            if (idx < TOT_CHUNKS) {
                const unsigned short* g = (idx < 512) ? wa + (size_t)idx * 8
                                                      : xb + (size_t)(idx - 512) * 8;
                GLOAD16(g, smem + idx * 16);
            }
        }
    }
    __syncthreads();

    for (int kt = 0; kt < NKT; ++kt) {
        int cur = kt & 1;
        if (kt + 1 < NKT) {   // stage next tile into other buffer (issued early)
            const unsigned short* wa = WAblk + (size_t)(kt + 1) * A_TILE;
            const unsigned short* xb = XBb + (size_t)(kt + 1) * B_TILE;
            char* nb = smem + (cur ^ 1) * TILE_BYTES;
            #pragma unroll
            for (int j = 0; j < 4; ++j) {
                int idx = tid + j * 256;
                if (idx < TOT_CHUNKS) {
                    const unsigned short* g = (idx < 512) ? wa + (size_t)idx * 8
                                                          : xb + (size_t)(idx - 512) * 8;
                    GLOAD16(g, nb + idx * 16);
                }
            }
        }
        const char* base = smem + cur * TILE_BYTES;
        f16x8 ah0 = *(const f16x8*)(base + aoff[0][0]);
        f16x8 ah1 = *(const f16x8*)(base + aoff[0][1]);
        f16x8 al0 = *(const f16x8*)(base + aoff[1][0]);
        f16x8 al1 = *(const f16x8*)(base + aoff[1][1]);
        f16x8 bf[4];
        #pragma unroll
        for (int nt = 0; nt < 4; ++nt)
            if (nt < NTW)
                bf[nt] = *(const f16x8*)(base + boff[nt]);
        #pragma unroll
        for (int nt = 0; nt < 4; ++nt) {
            if (nt >= NTW) continue;
            acc[0][nt] = __builtin_amdgcn_mfma_f32_16x16x32_f16(ah0, bf[nt], acc[0][nt], 0, 0, 0);
            acc[0][nt] = __builtin_amdgcn_mfma_f32_16x16x32_f16(al0, bf[nt], acc[0][nt], 0, 0, 0);
            acc[1][nt] = __builtin_amdgcn_mfma_f32_16x16x32_f16(ah1, bf[nt], acc[1][nt], 0, 0, 0);
            acc[1][nt] = __builtin_amdgcn_mfma_f32_16x16x32_f16(al1, bf[nt], acc[1][nt], 0, 0, 0);
        }
        __syncthreads();   // drains vmcnt -> next buffer ready; cur fully read
    }

    // ---- scan phase: reuse LDS ----
    float* zt = (float*)smem;                      // [64][101] f32 = 25856 B
    #pragma unroll
    for (int ar = 0; ar < 2; ++ar)
        #pragma unroll
        for (int nt = 0; nt < 4; ++nt) {
            if (nt >= NTW) continue;
            int t = wc * 64 + nt * 16 + lm;
            if (t < T) {
                #pragma unroll
                for (int r = 0; r < 4; ++r) {
                    int h = wr * 32 + ar * 16 + lg * 4 + r;
                    zt[h * 101 + t] = acc[ar][nt][r];
                }
            }
        }
    __syncthreads();

    if (tid < 64) {   // 64 LIF chains, one per h row
        float cur2 = 0.f, v = 0.f;
        for (int t = 0; t < T; ++t) {
            cur2 = fmaf(0.75f, cur2, zt[tid * 101 + t]);
            v    = fmaf(0.97f, v, cur2);
            float vpre = v;
            zt[tid * 101 + t] = vpre;
            v = (vpre >= 1.25f) ? 0.f : vpre;   // hard reset
        }
    }
    __syncthreads();

    // ---- global write-out S, V (spike recomputed from pre-reset voltage) ----
    size_t gbase = ((size_t)b * H + h0blk * 64) * T;
    for (int idx = tid; idx < 1600; idx += 256) {
        int h = idx / 25, q = idx - (idx / 25) * 25;
        int t0 = q * 4;
        f32x4 sv, vv;
        #pragma unroll
        for (int i = 0; i < 4; ++i) {
            float vpre = zt[h * 101 + t0 + i];
            vv[i] = vpre;
            sv[i] = (vpre >= 1.25f) ? 1.f : 0.f;
        }
        *(f32x4*)&S[gbase + (size_t)h * 100 + t0] = sv;
        *(f32x4*)&V[gbase + (size_t)h * 100 + t0] = vv;
    }
    // ---- spike image: two B-tiles (32 channels each) per block ----
    {
        unsigned short* dstb = sT + ((size_t)b * NKT1 + h0blk * 2) * B_TILE;
        for (int idx = tid; idx < 896; idx += 256) {
            int sub = idx / 448, c = idx - sub * 448;
            int g = c / 112, r = c - (c / 112) * 112;
            int ch0 = sub * 32 + g * 8;
            u16x8 outv;
            #pragma unroll
            for (int j = 0; j < 8; ++j) {
                bool sp = (r < T) && (zt[(ch0 + j) * 101 + r] >= 1.25f);
                outv[j] = sp ? 0x3C00 : 0;
            }
            *(u16x8*)&dstb[(size_t)idx * 8] = outv;
        }
    }
}

// ------ readout from images: R[l][b][o][t] = sum_h ro[o][h]*s[h][t], MFMA ------
__global__ __launch_bounds__(256) void readout_img(
    const unsigned short* __restrict__ r0img,  // [64][128 chunks][8]
    const unsigned short* __restrict__ r1img,
    const unsigned short* __restrict__ s0img,  // [64 b][64 kt][B_TILE]
    const unsigned short* __restrict__ s1img,
    float* __restrict__ R)                     // [2][B][O][T]
{
    __shared__ float red[4][2][7][4][64];      // 57344 B
    const int bid = blockIdx.x;
    const int l = bid >> 6, b = bid & 63;
    const unsigned short* ro = l ? r1img : r0img;
    const unsigned short* im = (l ? s1img : s0img) + (size_t)b * NKT1 * B_TILE;
    const int tid = threadIdx.x, lane = tid & 63, wave = tid >> 6;
    const int lm = lane & 15, lg = lane >> 4;

    f32x4 acc[2][7];
    #pragma unroll
    for (int ar = 0; ar < 2; ++ar)
        #pragma unroll
        for (int nt = 0; nt < 7; ++nt)
            acc[ar][nt] = (f32x4){0.f, 0.f, 0.f, 0.f};

    for (int kt = wave; kt < NKT1; kt += 4) {
        const unsigned short* A  = ro + (size_t)kt * 1024;
        const unsigned short* Bp = im + (size_t)kt * B_TILE;
        f16x8 a[2];
        #pragma unroll
        for (int ar = 0; ar < 2; ++ar) {
            int row = ar * 16 + lm;
            a[ar] = *(const f16x8*)&A[lg * 256 + row * 8];
        }
        #pragma unroll
        for (int nt = 0; nt < 7; ++nt) {
            int row = nt * 16 + lm;
            f16x8 bb = *(const f16x8*)&Bp[lg * 896 + row * 8];
            #pragma unroll
            for (int ar = 0; ar < 2; ++ar)
                acc[ar][nt] = __builtin_amdgcn_mfma_f32_16x16x32_f16(
                    a[ar], bb, acc[ar][nt], 0, 0, 0);
        }
    }
    #pragma unroll
    for (int ar = 0; ar < 2; ++ar)
        #pragma unroll
        for (int nt = 0; nt < 7; ++nt)
            #pragma unroll
            for (int r = 0; r < 4; ++r)
                red[wave][ar][nt][r][lane] = acc[ar][nt][r];
    __syncthreads();

    for (int idx = tid; idx < 3584; idx += 256) {
        int ln = idx & 63;
        int rest = idx >> 6;                 // 0..55
        int rg = rest & 3;
        int rest2 = rest >> 2;               // 0..13
        int nt = rest2 % 7, ar = rest2 / 7;
        float s = red[0][ar][nt][rg][ln] + red[1][ar][nt][rg][ln]
                + red[2][ar][nt][rg][ln] + red[3][ar][nt][rg][ln];
        int o = ar * 16 + (ln >> 4) * 4 + rg;
        int t = nt * 16 + (ln & 15);
        if (o < O && t < T)
            R[(((size_t)l * B + b) * O + o) * T + t] = s;
    }
}

// ---------------- standalone readout (fallback path only) ----------------
__global__ __launch_bounds__(128) void readout_kernel(
    const float* __restrict__ ro0, const float* __restrict__ ro1,
    const float* __restrict__ Sall, float* __restrict__ R)
{
    int bid = blockIdx.x;
    int l = bid / (B * O);
    int rem = bid - l * (B * O);
    int b = rem / O, o = rem - (rem / O) * O;
    int t = threadIdx.x;
    if (t >= T) return;
    const float* ro = (l == 0 ? ro0 : ro1) + (size_t)o * H;
    const float* s  = Sall + (size_t)l * B * H * T + (size_t)b * H * T + t;
    float acc = 0.f;
    #pragma unroll 8
    for (int h = 0; h < H; ++h)
        acc = fmaf(ro[h], s[(size_t)h * T], acc);
    R[(size_t)l * B * O * T + (size_t)b * O * T + (size_t)o * T + t] = acc;
}

// ---------------- fallback fp32 path (round-1, known correct) ----------------
__global__ __launch_bounds__(256) void gemm_scan_f32(
    const float* __restrict__ W, const float* __restrict__ X,
    int K, long xbs, float* __restrict__ S, float* __restrict__ V)
{
    __shared__ float fxs[16][112];
    __shared__ float fwl[64][16];
    __shared__ float fzt[64][101];
    __shared__ float fst[64][101];
    const int tid = threadIdx.x;
    const int tx = tid & 15, ty = tid >> 4;
    const int b = blockIdx.y, h0 = blockIdx.x * 64;
    const float* Xb = X + (long)b * xbs;
    float acc[4][7];
    #pragma unroll
    for (int k = 0; k < 4; ++k)
        #pragma unroll
        for (int j = 0; j < 7; ++j) acc[k][j] = 0.f;
    for (int cc = 0; cc < K; cc += 16) {
        for (int idx = tid; idx < 16 * 112; idx += 256) {
            int c = idx / 112, t = idx - c * 112;
            float v = 0.f;
            if (t < T && cc + c < K) v = Xb[(long)(cc + c) * T + t];
            fxs[c][t] = v;
        }
        for (int idx = tid; idx < 64 * 16; idx += 256) {
            int h = idx >> 4, c = idx & 15;
            float v = 0.f;
            if (cc + c < K) v = W[(long)(h0 + h) * K + cc + c];
            fwl[h][c] = v;
        }
        __syncthreads();
        #pragma unroll
        for (int c = 0; c < 16; ++c) {
            float wv[4], xv[7];
            #pragma unroll
            for (int k = 0; k < 4; ++k) wv[k] = fwl[ty + 16 * k][c];
            #pragma unroll
            for (int j = 0; j < 7; ++j) xv[j] = fxs[c][tx + 16 * j];
            #pragma unroll
            for (int k = 0; k < 4; ++k)
                #pragma unroll
                for (int j = 0; j < 7; ++j)
                    acc[k][j] = fmaf(wv[k], xv[j], acc[k][j]);
        }
        __syncthreads();
    }
    #pragma unroll
    for (int k = 0; k < 4; ++k)
        #pragma unroll
        for (int j = 0; j < 7; ++j) {
            int t = tx + 16 * j;
            if (t < T) fzt[ty + 16 * k][t] = acc[k][j];
        }
    __syncthreads();
    if (tid < 64) {
        float cur = 0.f, v = 0.f;
        for (int t = 0; t < T; ++t) {
            cur = fmaf(0.75f, cur, fzt[tid][t]);
            v = fmaf(0.97f, v, cur);
            float s = (v >= 1.25f) ? 1.f : 0.f;
            fst[tid][t] = s;
            fzt[tid][t] = v;
            v *= (1.f - s);
        }
    }
    __syncthreads();
    long base = (long)b * H * T + (long)h0 * T;
    for (int idx = tid; idx < 64 * T; idx += 256) {
        int h = idx / T, t = idx - (idx / T) * T;
        S[base + idx] = fst[h][t];
        V[base + idx] = fzt[h][t];
    }
}

extern "C" void kernel_launch(void* const* d_in, const int* in_sizes, int n_in,
                              void* d_out, int out_size, void* d_ws, size_t ws_size,
                              hipStream_t stream) {
    const float* spike = (const float*)d_in[0];
    const float* w0    = (const float*)d_in[1];
    const float* w1    = (const float*)d_in[2];
    const float* ro0   = (const float*)d_in[3];
    const float* ro1   = (const float*)d_in[4];

    float* out = (float*)d_out;
    float* S = out;
    float* R = out + 2L * B * H * T;
    float* V = out + 2L * B * H * T + 2L * B * O * T;

    const size_t nW0 = (size_t)32 * NKT0 * A_TILE;
    const size_t nW1 = (size_t)32 * NKT1 * A_TILE;
    const size_t nX0 = (size_t)B * NKT0 * B_TILE;
    const size_t nS  = (size_t)B * NKT1 * B_TILE;   // per-layer spike image
    const size_t nRO = (size_t)NKT1 * 1024;         // per-layer ro image
    const size_t need = (nW0 + nW1 + nX0 + 2 * nS + 2 * nRO) * sizeof(unsigned short);

    if (ws_size >= need) {
        unsigned short* p = (unsigned short*)d_ws;
        unsigned short* w0img = p; p += nW0;
        unsigned short* w1img = p; p += nW1;
        unsigned short* x0img = p; p += nX0;
        unsigned short* s0img = p; p += nS;
        unsigned short* s1img = p; p += nS;
        unsigned short* r0img = p; p += nRO;
        unsigned short* r1img = p; p += nRO;

        prepass_all<<<PRE_BLKS, 256, 0, stream>>>(spike, w0, w1, ro0, ro1,
                                                  w0img, w1img, x0img,
                                                  r0img, r1img);

        gemm_scan_mfma4<<<2048, 256, 0, stream>>>(w0img, x0img, NKT0, S, V, s0img);
        gemm_scan_mfma4<<<2048, 256, 0, stream>>>(w1img, s0img, NKT1,
                                                  S + (size_t)B * H * T,
                                                  V + (size_t)B * H * T, s1img);
        readout_img<<<128, 256, 0, stream>>>(r0img, r1img, s0img, s1img, R);
    } else {
        dim3 grid(H / 64, B);
        gemm_scan_f32<<<grid, 256, 0, stream>>>(w0, spike, I, (long)I * T, S, V);
        gemm_scan_f32<<<grid, 256, 0, stream>>>(w1, S, H, (long)H * T,
                                                S + (long)B * H * T, V + (long)B * H * T);
        readout_kernel<<<2 * B * O, 128, 0, stream>>>(ro0, ro1, S, R);
    }
}

// Round 16
// 207.212 us; speedup vs baseline: 1.1173x; 1.0461x over previous
//
#include <hip/hip_runtime.h>

using f16x8 = __attribute__((ext_vector_type(8))) _Float16;
using f32x4 = __attribute__((ext_vector_type(4))) float;
using u16x8 = __attribute__((ext_vector_type(8))) unsigned short;

constexpr int B = 64, I = 700, H = 2048, O = 20, T = 100;
constexpr int NKT0 = 22;        // K-tiles layer 0 (704 = 22*32)
constexpr int NKT1 = 64;        // K-tiles layer 1 (2048 = 64*32)
// v2 tile layout (k-group-major, chunk-linear, bank-conflict-free):
//   A tile: [4 g][128 rows (64 hi + 64 lo)][8 f16]  = 512 chunks = 4096 ushorts
//   B tile: [4 g][112 rows (t)][8 f16]              = 448 chunks = 3584 ushorts
constexpr int A_TILE = 4096;    // ushorts
constexpr int B_TILE = 3584;    // ushorts
constexpr int TILE_BYTES = 15360;
constexpr int TOT_CHUNKS = 960; // 512 A + 448 B

// merged prepass block ranges
constexpr int PW0_BLKS = (32 * NKT0 * 512) / 256;   // 1408
constexpr int PW1_BLKS = (32 * NKT1 * 512) / 256;   // 4096
constexpr int PX_BLKS  = NKT0 * B;                  // 1408
constexpr int PRO_BLKS = NKT1;                      // 64 (both layers per block)
constexpr int PRE_BLKS = PW0_BLKS + PW1_BLKS + PX_BLKS + PRO_BLKS;

#define GLOAD16(gp, lp) __builtin_amdgcn_global_load_lds( \
    (const __attribute__((address_space(1))) unsigned int*)(const void*)(gp), \
    (__attribute__((address_space(3))) unsigned int*)(void*)(lp), 16, 0, 0)

// ---------------- merged pre-pass bodies ----------------
__device__ inline void conv_w_body(const float* __restrict__ w, int K, int NKT,
                                   int idx, unsigned short* __restrict__ dst)
{
    int c = idx & 511, img = idx >> 9;
    int h0blk = img / NKT, kt = img - h0blk * NKT;
    int g = c >> 7, row = c & 127;
    int sp = row >> 6, hr = row & 63;
    int kbase = kt * 32 + g * 8;
    const float* wrow = w + (size_t)(h0blk * 64 + hr) * K;
    u16x8 outv;
    #pragma unroll
    for (int j = 0; j < 8; ++j) {
        int k = kbase + j;
        float f = (k < K) ? wrow[k] : 0.f;
        _Float16 hi = (_Float16)f;
        _Float16 val = (sp == 0) ? hi : (_Float16)(f - (float)hi);
        outv[j] = *(unsigned short*)&val;
    }
    *(u16x8*)&dst[(size_t)idx * 8] = outv;
}

__global__ __launch_bounds__(256) void prepass_all(
    const float* __restrict__ spike,
    const float* __restrict__ w0, const float* __restrict__ w1,
    const float* __restrict__ ro0, const float* __restrict__ ro1,
    unsigned short* __restrict__ w0img, unsigned short* __restrict__ w1img,
    unsigned short* __restrict__ x0img,
    unsigned short* __restrict__ r0img, unsigned short* __restrict__ r1img)
{
    __shared__ float xs[32][101];
    int bid = blockIdx.x;
    if (bid < PW0_BLKS) {
        conv_w_body(w0, I, NKT0, bid * 256 + threadIdx.x, w0img);
    } else if (bid < PW0_BLKS + PW1_BLKS) {
        conv_w_body(w1, H, NKT1, (bid - PW0_BLKS) * 256 + threadIdx.x, w1img);
    } else if (bid < PW0_BLKS + PW1_BLKS + PX_BLKS) {
        // X transpose: fp32 [B][I][T] -> B-tiles (v2 layout)
        int q = bid - (PW0_BLKS + PW1_BLKS);
        int kt = q % NKT0, b = q / NKT0;
        int c0 = kt * 32;
        const float* Xb = spike + (size_t)b * I * T;
        for (int idx = threadIdx.x; idx < 32 * T; idx += 256) {
            int ci = idx / T, t = idx - (idx / T) * T;
            xs[ci][t] = (c0 + ci < I) ? Xb[(size_t)(c0 + ci) * T + t] : 0.f;
        }
        __syncthreads();
        unsigned short* dst = x0img + ((size_t)b * NKT0 + kt) * B_TILE;
        for (int idx = threadIdx.x; idx < 448; idx += 256) {
            int g = idx / 112, r = idx - (idx / 112) * 112;
            u16x8 outv;
            #pragma unroll
            for (int j = 0; j < 8; ++j) {
                float f = (r < T) ? xs[g * 8 + j][r] : 0.f;
                _Float16 h = (_Float16)f;
                outv[j] = *(unsigned short*)&h;
            }
            *(u16x8*)&dst[(size_t)idx * 8] = outv;
        }
    } else {
        // ro conversion, both layers: [O][H] -> per-kt32 A-tiles
        int kt = bid - (PW0_BLKS + PW1_BLKS + PX_BLKS);
        int l = threadIdx.x >> 7, c = threadIdx.x & 127;
        const float* ro = l ? ro1 : ro0;
        unsigned short* dst = l ? r1img : r0img;
        int g = c >> 5, row = c & 31;
        int k0 = kt * 32 + g * 8;
        u16x8 outv;
        #pragma unroll
        for (int j = 0; j < 8; ++j) {
            float f = (row < O) ? ro[(size_t)row * H + k0 + j] : 0.f;
            _Float16 hv = (_Float16)f;
            outv[j] = *(unsigned short*)&hv;
        }
        *(u16x8*)&dst[((size_t)kt * 128 + c) * 8] = outv;
    }
}

// ------ fused MFMA GEMM (BK=32, 2-phase gload_lds, 5 blocks/CU) + CUBA scan ----
// (round-9 champion; S/V writes made nontemporal to keep W/X tiles L2-hot)
__global__ __launch_bounds__(256, 4) void gemm_scan_mfma4(
    const unsigned short* __restrict__ WA,   // [32][NKT][A_TILE]
    const unsigned short* __restrict__ XB,   // [64][NKT][B_TILE]
    int NKT,
    float* __restrict__ S, float* __restrict__ V,
    unsigned short* __restrict__ sT)         // [64][NKT1][B_TILE] spike image out
{
    __shared__ __align__(16) char smem[2 * TILE_BYTES];   // 30720 B (scan overlays)
    const int tid = threadIdx.x;
    const int lane = tid & 63, wave = tid >> 6;
    const int lm = lane & 15, lg = lane >> 4;
    const int wr = wave >> 1, wc = wave & 1;
    const int NTW = 4 - wc;

    // XCD-aware decode: blocks with same b land on same XCD
    int orig = blockIdx.x;
    int xcd = orig & 7, slot = orig >> 3;
    int b = xcd * 8 + (slot & 7);
    int h0blk = slot >> 3;

    const unsigned short* WAblk = WA + (size_t)h0blk * NKT * A_TILE;
    const unsigned short* XBb   = XB + (size_t)b * NKT * B_TILE;

    // fragment byte offsets within one buffer (kt-invariant)
    int aoff[2][2], boff[4];
    #pragma unroll
    for (int sp = 0; sp < 2; ++sp)
        #pragma unroll
        for (int ar = 0; ar < 2; ++ar) {
            int row = sp * 64 + wr * 32 + ar * 16 + lm;
            aoff[sp][ar] = lg * 2048 + row * 16;
        }
    #pragma unroll
    for (int nt = 0; nt < 4; ++nt) {
        int row = wc * 64 + nt * 16 + lm;
        boff[nt] = 8192 + lg * 1792 + row * 16;
    }

    f32x4 acc[2][4];
    #pragma unroll
    for (int ar = 0; ar < 2; ++ar)
        #pragma unroll
        for (int nt = 0; nt < 4; ++nt)
            acc[ar][nt] = (f32x4){0.f, 0.f, 0.f, 0.f};

    // prologue: stage kt=0 into buf 0
    {
        const unsigned short* wa = WAblk;
        const unsigned short* xb = XBb;
        #pragma unroll
        for (int j = 0; j < 4; ++j) {
            int idx = tid + j * 256;
            if (idx < TOT_CHUNKS) {
                const unsigned short* g = (idx < 512) ? wa + (size_t)idx * 8
                                                      : xb + (size_t)(idx - 512) * 8;
                GLOAD16(g, smem + idx * 16);
            }
        }
    }
    __syncthreads();

    for (int kt = 0; kt < NKT; ++kt) {
        int cur = kt & 1;
        if (kt + 1 < NKT) {   // stage next tile into other buffer (issued early)
            const unsigned short* wa = WAblk + (size_t)(kt + 1) * A_TILE;
            const unsigned short* xb = XBb + (size_t)(kt + 1) * B_TILE;
            char* nb = smem + (cur ^ 1) * TILE_BYTES;
            #pragma unroll
            for (int j = 0; j < 4; ++j) {
                int idx = tid + j * 256;
                if (idx < TOT_CHUNKS) {
                    const unsigned short* g = (idx < 512) ? wa + (size_t)idx * 8
                                                          : xb + (size_t)(idx - 512) * 8;
                    GLOAD16(g, nb + idx * 16);
                }
            }
        }
        const char* base = smem + cur * TILE_BYTES;
        f16x8 ah0 = *(const f16x8*)(base + aoff[0][0]);
        f16x8 ah1 = *(const f16x8*)(base + aoff[0][1]);
        f16x8 al0 = *(const f16x8*)(base + aoff[1][0]);
        f16x8 al1 = *(const f16x8*)(base + aoff[1][1]);
        f16x8 bf[4];
        #pragma unroll
        for (int nt = 0; nt < 4; ++nt)
            if (nt < NTW)
                bf[nt] = *(const f16x8*)(base + boff[nt]);
        #pragma unroll
        for (int nt = 0; nt < 4; ++nt) {
            if (nt >= NTW) continue;
            acc[0][nt] = __builtin_amdgcn_mfma_f32_16x16x32_f16(ah0, bf[nt], acc[0][nt], 0, 0, 0);
            acc[0][nt] = __builtin_amdgcn_mfma_f32_16x16x32_f16(al0, bf[nt], acc[0][nt], 0, 0, 0);
            acc[1][nt] = __builtin_amdgcn_mfma_f32_16x16x32_f16(ah1, bf[nt], acc[1][nt], 0, 0, 0);
            acc[1][nt] = __builtin_amdgcn_mfma_f32_16x16x32_f16(al1, bf[nt], acc[1][nt], 0, 0, 0);
        }
        __syncthreads();   // drains vmcnt -> next buffer ready; cur fully read
    }

    // ---- scan phase: reuse LDS ----
    float* zt = (float*)smem;                      // [64][101] f32 = 25856 B
    #pragma unroll
    for (int ar = 0; ar < 2; ++ar)
        #pragma unroll
        for (int nt = 0; nt < 4; ++nt) {
            if (nt >= NTW) continue;
            int t = wc * 64 + nt * 16 + lm;
            if (t < T) {
                #pragma unroll
                for (int r = 0; r < 4; ++r) {
                    int h = wr * 32 + ar * 16 + lg * 4 + r;
                    zt[h * 101 + t] = acc[ar][nt][r];
                }
            }
        }
    __syncthreads();

    if (tid < 64) {   // 64 LIF chains, one per h row
        float cur2 = 0.f, v = 0.f;
        for (int t = 0; t < T; ++t) {
            cur2 = fmaf(0.75f, cur2, zt[tid * 101 + t]);
            v    = fmaf(0.97f, v, cur2);
            float vpre = v;
            zt[tid * 101 + t] = vpre;
            v = (vpre >= 1.25f) ? 0.f : vpre;   // hard reset
        }
    }
    __syncthreads();

    // ---- global write-out S, V: NONTEMPORAL (never re-read; keep L2 for tiles) ----
    size_t gbase = ((size_t)b * H + h0blk * 64) * T;
    for (int idx = tid; idx < 1600; idx += 256) {
        int h = idx / 25, q = idx - (idx / 25) * 25;
        int t0 = q * 4;
        f32x4 sv, vv;
        #pragma unroll
        for (int i = 0; i < 4; ++i) {
            float vpre = zt[h * 101 + t0 + i];
            vv[i] = vpre;
            sv[i] = (vpre >= 1.25f) ? 1.f : 0.f;
        }
        __builtin_nontemporal_store(sv, (f32x4*)&S[gbase + (size_t)h * 100 + t0]);
        __builtin_nontemporal_store(vv, (f32x4*)&V[gbase + (size_t)h * 100 + t0]);
    }
    // ---- spike image (cached: re-read by same-XCD consumers next dispatch) ----
    {
        unsigned short* dstb = sT + ((size_t)b * NKT1 + h0blk * 2) * B_TILE;
        for (int idx = tid; idx < 896; idx += 256) {
            int sub = idx / 448, c = idx - sub * 448;
            int g = c / 112, r = c - (c / 112) * 112;
            int ch0 = sub * 32 + g * 8;
            u16x8 outv;
            #pragma unroll
            for (int j = 0; j < 8; ++j) {
                bool sp = (r < T) && (zt[(ch0 + j) * 101 + r] >= 1.25f);
                outv[j] = sp ? 0x3C00 : 0;
            }
            *(u16x8*)&dstb[(size_t)idx * 8] = outv;
        }
    }
}

// ------ readout from images: R[l][b][o][t] = sum_h ro[o][h]*s[h][t], MFMA ------
__global__ __launch_bounds__(256) void readout_img(
    const unsigned short* __restrict__ r0img,  // [64][128 chunks][8]
    const unsigned short* __restrict__ r1img,
    const unsigned short* __restrict__ s0img,  // [64 b][64 kt][B_TILE]
    const unsigned short* __restrict__ s1img,
    float* __restrict__ R)                     // [2][B][O][T]
{
    __shared__ float red[4][2][7][4][64];      // 57344 B
    const int bid = blockIdx.x;
    const int l = bid >> 6, b = bid & 63;
    const unsigned short* ro = l ? r1img : r0img;
    const unsigned short* im = (l ? s1img : s0img) + (size_t)b * NKT1 * B_TILE;
    const int tid = threadIdx.x, lane = tid & 63, wave = tid >> 6;
    const int lm = lane & 15, lg = lane >> 4;

    f32x4 acc[2][7];
    #pragma unroll
    for (int ar = 0; ar < 2; ++ar)
        #pragma unroll
        for (int nt = 0; nt < 7; ++nt)
            acc[ar][nt] = (f32x4){0.f, 0.f, 0.f, 0.f};

    for (int kt = wave; kt < NKT1; kt += 4) {
        const unsigned short* A  = ro + (size_t)kt * 1024;
        const unsigned short* Bp = im + (size_t)kt * B_TILE;
        f16x8 a[2];
        #pragma unroll
        for (int ar = 0; ar < 2; ++ar) {
            int row = ar * 16 + lm;
            a[ar] = *(const f16x8*)&A[lg * 256 + row * 8];
        }
        #pragma unroll
        for (int nt = 0; nt < 7; ++nt) {
            int row = nt * 16 + lm;
            f16x8 bb = *(const f16x8*)&Bp[lg * 896 + row * 8];
            #pragma unroll
            for (int ar = 0; ar < 2; ++ar)
                acc[ar][nt] = __builtin_amdgcn_mfma_f32_16x16x32_f16(
                    a[ar], bb, acc[ar][nt], 0, 0, 0);
        }
    }
    #pragma unroll
    for (int ar = 0; ar < 2; ++ar)
        #pragma unroll
        for (int nt = 0; nt < 7; ++nt)
            #pragma unroll
            for (int r = 0; r < 4; ++r)
                red[wave][ar][nt][r][lane] = acc[ar][nt][r];
    __syncthreads();

    for (int idx = tid; idx < 3584; idx += 256) {
        int ln = idx & 63;
        int rest = idx >> 6;                 // 0..55
        int rg = rest & 3;
        int rest2 = rest >> 2;               // 0..13
        int nt = rest2 % 7, ar = rest2 / 7;
        float s = red[0][ar][nt][rg][ln] + red[1][ar][nt][rg][ln]
                + red[2][ar][nt][rg][ln] + red[3][ar][nt][rg][ln];
        int o = ar * 16 + (ln >> 4) * 4 + rg;
        int t = nt * 16 + (ln & 15);
        if (o < O && t < T)
            R[(((size_t)l * B + b) * O + o) * T + t] = s;
    }
}

// ---------------- standalone readout (fallback path only) ----------------
__global__ __launch_bounds__(128) void readout_kernel(
    const float* __restrict__ ro0, const float* __restrict__ ro1,
    const float* __restrict__ Sall, float* __restrict__ R)
{
    int bid = blockIdx.x;
    int l = bid / (B * O);
    int rem = bid - l * (B * O);
    int b = rem / O, o = rem - (rem / O) * O;
    int t = threadIdx.x;
    if (t >= T) return;
    const float* ro = (l == 0 ? ro0 : ro1) + (size_t)o * H;
    const float* s  = Sall + (size_t)l * B * H * T + (size_t)b * H * T + t;
    float acc = 0.f;
    #pragma unroll 8
    for (int h = 0; h < H; ++h)
        acc = fmaf(ro[h], s[(size_t)h * T], acc);
    R[(size_t)l * B * O * T + (size_t)b * O * T + (size_t)o * T + t] = acc;
}

// ---------------- fallback fp32 path (round-1, known correct) ----------------
__global__ __launch_bounds__(256) void gemm_scan_f32(
    const float* __restrict__ W, const float* __restrict__ X,
    int K, long xbs, float* __restrict__ S, float* __restrict__ V)
{
    __shared__ float fxs[16][112];
    __shared__ float fwl[64][16];
    __shared__ float fzt[64][101];
    __shared__ float fst[64][101];
    const int tid = threadIdx.x;
    const int tx = tid & 15, ty = tid >> 4;
    const int b = blockIdx.y, h0 = blockIdx.x * 64;
    const float* Xb = X + (long)b * xbs;
    float acc[4][7];
    #pragma unroll
    for (int k = 0; k < 4; ++k)
        #pragma unroll
        for (int j = 0; j < 7; ++j) acc[k][j] = 0.f;
    for (int cc = 0; cc < K; cc += 16) {
        for (int idx = tid; idx < 16 * 112; idx += 256) {
            int c = idx / 112, t = idx - c * 112;
            float v = 0.f;
            if (t < T && cc + c < K) v = Xb[(long)(cc + c) * T + t];
            fxs[c][t] = v;
        }
        for (int idx = tid; idx < 64 * 16; idx += 256) {
            int h = idx >> 4, c = idx & 15;
            float v = 0.f;
            if (cc + c < K) v = W[(long)(h0 + h) * K + cc + c];
            fwl[h][c] = v;
        }
        __syncthreads();
        #pragma unroll
        for (int c = 0; c < 16; ++c) {
            float wv[4], xv[7];
            #pragma unroll
            for (int k = 0; k < 4; ++k) wv[k] = fwl[ty + 16 * k][c];
            #pragma unroll
            for (int j = 0; j < 7; ++j) xv[j] = fxs[c][tx + 16 * j];
            #pragma unroll
            for (int k = 0; k < 4; ++k)
                #pragma unroll
                for (int j = 0; j < 7; ++j)
                    acc[k][j] = fmaf(wv[k], xv[j], acc[k][j]);
        }
        __syncthreads();
    }
    #pragma unroll
    for (int k = 0; k < 4; ++k)
        #pragma unroll
        for (int j = 0; j < 7; ++j) {
            int t = tx + 16 * j;
            if (t < T) fzt[ty + 16 * k][t] = acc[k][j];
        }
    __syncthreads();
    if (tid < 64) {
        float cur = 0.f, v = 0.f;
        for (int t = 0; t < T; ++t) {
            cur = fmaf(0.75f, cur, fzt[tid][t]);
            v = fmaf(0.97f, v, cur);
            float s = (v >= 1.25f) ? 1.f : 0.f;
            fst[tid][t] = s;
            fzt[tid][t] = v;
            v *= (1.f - s);
        }
    }
    __syncthreads();
    long base = (long)b * H * T + (long)h0 * T;
    for (int idx = tid; idx < 64 * T; idx += 256) {
        int h = idx / T, t = idx - (idx / T) * T;
        S[base + idx] = fst[h][t];
        V[base + idx] = fzt[h][t];
    }
}

extern "C" void kernel_launch(void* const* d_in, const int* in_sizes, int n_in,
                              void* d_out, int out_size, void* d_ws, size_t ws_size,
                              hipStream_t stream) {
    const float* spike = (const float*)d_in[0];
    const float* w0    = (const float*)d_in[1];
    const float* w1    = (const float*)d_in[2];
    const float* ro0   = (const float*)d_in[3];
    const float* ro1   = (const float*)d_in[4];

    float* out = (float*)d_out;
    float* S = out;
    float* R = out + 2L * B * H * T;
    float* V = out + 2L * B * H * T + 2L * B * O * T;

    const size_t nW0 = (size_t)32 * NKT0 * A_TILE;
    const size_t nW1 = (size_t)32 * NKT1 * A_TILE;
    const size_t nX0 = (size_t)B * NKT0 * B_TILE;
    const size_t nS  = (size_t)B * NKT1 * B_TILE;   // per-layer spike image
    const size_t nRO = (size_t)NKT1 * 1024;         // per-layer ro image
    const size_t need = (nW0 + nW1 + nX0 + 2 * nS + 2 * nRO) * sizeof(unsigned short);

    if (ws_size >= need) {
        unsigned short* p = (unsigned short*)d_ws;
        unsigned short* w0img = p; p += nW0;
        unsigned short* w1img = p; p += nW1;
        unsigned short* x0img = p; p += nX0;
        unsigned short* s0img = p; p += nS;
        unsigned short* s1img = p; p += nS;
        unsigned short* r0img = p; p += nRO;
        unsigned short* r1img = p; p += nRO;

        prepass_all<<<PRE_BLKS, 256, 0, stream>>>(spike, w0, w1, ro0, ro1,
                                                  w0img, w1img, x0img,
                                                  r0img, r1img);

        gemm_scan_mfma4<<<2048, 256, 0, stream>>>(w0img, x0img, NKT0, S, V, s0img);
        gemm_scan_mfma4<<<2048, 256, 0, stream>>>(w1img, s0img, NKT1,
                                                  S + (size_t)B * H * T,
                                                  V + (size_t)B * H * T, s1img);
        readout_img<<<128, 256, 0, stream>>>(r0img, r1img, s0img, s1img, R);
    } else {
        dim3 grid(H / 64, B);
        gemm_scan_f32<<<grid, 256, 0, stream>>>(w0, spike, I, (long)I * T, S, V);
        gemm_scan_f32<<<grid, 256, 0, stream>>>(w1, S, H, (long)H * T,
                                                S + (long)B * H * T, V + (long)B * H * T);
        readout_kernel<<<2 * B * O, 128, 0, stream>>>(ro0, ro1, S, R);
    }
}

// Round 17
// 183.703 us; speedup vs baseline: 1.2603x; 1.1280x over previous
//
#include <hip/hip_runtime.h>

using f16x8 = __attribute__((ext_vector_type(8))) _Float16;
using f32x4 = __attribute__((ext_vector_type(4))) float;
using u16x8 = __attribute__((ext_vector_type(8))) unsigned short;

constexpr int B = 64, I = 700, H = 2048, O = 20, T = 100;
constexpr int NKT0 = 22;        // K-tiles layer 0 (704 = 22*32)
constexpr int NKT1 = 64;        // K-tiles layer 1 (2048 = 64*32)
// tile layouts (k-group-major, chunk-linear):
//   A split tile  : [4 g][128 rows (64 hi + 64 lo)][8 f16] = 512 chunks
//   A hi-only tile: [4 g][ 64 rows           ][8 f16]      = 256 chunks
//   B tile        : [4 g][112 rows (t)][8 f16]             = 448 chunks
constexpr int A_TILE_S = 4096;  // ushorts (split)
constexpr int A_TILE_H = 2048;  // ushorts (hi-only)
constexpr int B_TILE = 3584;    // ushorts

// merged prepass block ranges
constexpr int PW0_BLKS = (32 * NKT0 * 512) / 256;   // 1408 (split tiles)
constexpr int PW1_BLKS = (32 * NKT1 * 256) / 256;   // 2048 (hi-only tiles)
constexpr int PX_BLKS  = NKT0 * B;                  // 1408
constexpr int PRO_BLKS = NKT1;                      // 64 (both layers per block)
constexpr int PRE_BLKS = PW0_BLKS + PW1_BLKS + PX_BLKS + PRO_BLKS;

#define GLOAD16(gp, lp) __builtin_amdgcn_global_load_lds( \
    (const __attribute__((address_space(1))) unsigned int*)(const void*)(gp), \
    (__attribute__((address_space(3))) unsigned int*)(void*)(lp), 16, 0, 0)

// ---------------- merged pre-pass bodies ----------------
__device__ inline void conv_w_split_body(const float* __restrict__ w, int K, int NKT,
                                         int idx, unsigned short* __restrict__ dst)
{
    int c = idx & 511, img = idx >> 9;
    int h0blk = img / NKT, kt = img - h0blk * NKT;
    int g = c >> 7, row = c & 127;
    int sp = row >> 6, hr = row & 63;
    int kbase = kt * 32 + g * 8;
    const float* wrow = w + (size_t)(h0blk * 64 + hr) * K;
    u16x8 outv;
    #pragma unroll
    for (int j = 0; j < 8; ++j) {
        int k = kbase + j;
        float f = (k < K) ? wrow[k] : 0.f;
        _Float16 hi = (_Float16)f;
        _Float16 val = (sp == 0) ? hi : (_Float16)(f - (float)hi);
        outv[j] = *(unsigned short*)&val;
    }
    *(u16x8*)&dst[(size_t)idx * 8] = outv;
}

__device__ inline void conv_w_hi_body(const float* __restrict__ w, int K, int NKT,
                                      int idx, unsigned short* __restrict__ dst)
{
    int c = idx & 255, img = idx >> 8;
    int h0blk = img / NKT, kt = img - h0blk * NKT;
    int g = c >> 6, row = c & 63;
    int kbase = kt * 32 + g * 8;
    const float* wrow = w + (size_t)(h0blk * 64 + row) * K;
    u16x8 outv;
    #pragma unroll
    for (int j = 0; j < 8; ++j) {
        int k = kbase + j;
        float f = (k < K) ? wrow[k] : 0.f;
        _Float16 hv = (_Float16)f;
        outv[j] = *(unsigned short*)&hv;
    }
    *(u16x8*)&dst[(size_t)idx * 8] = outv;
}

__global__ __launch_bounds__(256) void prepass_all(
    const float* __restrict__ spike,
    const float* __restrict__ w0, const float* __restrict__ w1,
    const float* __restrict__ ro0, const float* __restrict__ ro1,
    unsigned short* __restrict__ w0img, unsigned short* __restrict__ w1img,
    unsigned short* __restrict__ x0img,
    unsigned short* __restrict__ r0img, unsigned short* __restrict__ r1img)
{
    __shared__ float xs[32][101];
    int bid = blockIdx.x;
    if (bid < PW0_BLKS) {
        conv_w_split_body(w0, I, NKT0, bid * 256 + threadIdx.x, w0img);
    } else if (bid < PW0_BLKS + PW1_BLKS) {
        conv_w_hi_body(w1, H, NKT1, (bid - PW0_BLKS) * 256 + threadIdx.x, w1img);
    } else if (bid < PW0_BLKS + PW1_BLKS + PX_BLKS) {
        // X transpose: fp32 [B][I][T] -> B-tiles
        int q = bid - (PW0_BLKS + PW1_BLKS);
        int kt = q % NKT0, b = q / NKT0;
        int c0 = kt * 32;
        const float* Xb = spike + (size_t)b * I * T;
        for (int idx = threadIdx.x; idx < 32 * T; idx += 256) {
            int ci = idx / T, t = idx - (idx / T) * T;
            xs[ci][t] = (c0 + ci < I) ? Xb[(size_t)(c0 + ci) * T + t] : 0.f;
        }
        __syncthreads();
        unsigned short* dst = x0img + ((size_t)b * NKT0 + kt) * B_TILE;
        for (int idx = threadIdx.x; idx < 448; idx += 256) {
            int g = idx / 112, r = idx - (idx / 112) * 112;
            u16x8 outv;
            #pragma unroll
            for (int j = 0; j < 8; ++j) {
                float f = (r < T) ? xs[g * 8 + j][r] : 0.f;
                _Float16 h = (_Float16)f;
                outv[j] = *(unsigned short*)&h;
            }
            *(u16x8*)&dst[(size_t)idx * 8] = outv;
        }
    } else {
        // ro conversion, both layers: [O][H] -> per-kt32 A-tiles
        int kt = bid - (PW0_BLKS + PW1_BLKS + PX_BLKS);
        int l = threadIdx.x >> 7, c = threadIdx.x & 127;
        const float* ro = l ? ro1 : ro0;
        unsigned short* dst = l ? r1img : r0img;
        int g = c >> 5, row = c & 31;
        int k0 = kt * 32 + g * 8;
        u16x8 outv;
        #pragma unroll
        for (int j = 0; j < 8; ++j) {
            float f = (row < O) ? ro[(size_t)row * H + k0 + j] : 0.f;
            _Float16 hv = (_Float16)f;
            outv[j] = *(unsigned short*)&hv;
        }
        *(u16x8*)&dst[((size_t)kt * 128 + c) * 8] = outv;
    }
}

// ------ fused MFMA GEMM (BK=32, 2-phase gload_lds) + CUBA scan ----------------
// SPLIT=1: hi+lo f16 weights (layer 0). SPLIT=0: hi-only (layer 1, half FLOPs).
template <int SPLIT>
__global__ __launch_bounds__(256, 4) void gemm_scan_t(
    const unsigned short* __restrict__ WA,
    const unsigned short* __restrict__ XB,
    int NKT,
    float* __restrict__ S, float* __restrict__ V,
    unsigned short* __restrict__ sT)
{
    constexpr int A_CH = SPLIT ? 512 : 256;        // A chunks per tile
    constexpr int TOT  = A_CH + 448;               // total chunks per tile
    constexpr int TBYTES = TOT * 16;               // LDS bytes per buffer
    constexpr int A_ELEMS = A_CH * 8;              // A image ushorts per kt
    constexpr int NSTG = (TOT + 255) / 256;        // staging iterations

    __shared__ __align__(16) char smem[2 * 15360]; // max-size; scan overlays
    const int tid = threadIdx.x;
    const int lane = tid & 63, wave = tid >> 6;
    const int lm = lane & 15, lg = lane >> 4;
    const int wr = wave >> 1, wc = wave & 1;
    const int NTW = 4 - wc;

    // XCD-aware decode: blocks with same b land on same XCD
    int orig = blockIdx.x;
    int xcd = orig & 7, slot = orig >> 3;
    int b = xcd * 8 + (slot & 7);
    int h0blk = slot >> 3;

    const unsigned short* WAblk = WA + (size_t)h0blk * NKT * A_ELEMS;
    const unsigned short* XBb   = XB + (size_t)b * NKT * B_TILE;

    // fragment byte offsets within one buffer (kt-invariant)
    int aoff[2][2], boff[4];
    #pragma unroll
    for (int sp = 0; sp < (SPLIT ? 2 : 1); ++sp)
        #pragma unroll
        for (int ar = 0; ar < 2; ++ar) {
            int row = sp * 64 + wr * 32 + ar * 16 + lm;
            aoff[sp][ar] = lg * (SPLIT ? 2048 : 1024) + row * 16;
        }
    #pragma unroll
    for (int nt = 0; nt < 4; ++nt) {
        int row = wc * 64 + nt * 16 + lm;
        boff[nt] = A_CH * 16 + lg * 1792 + row * 16;
    }

    f32x4 acc[2][4];
    #pragma unroll
    for (int ar = 0; ar < 2; ++ar)
        #pragma unroll
        for (int nt = 0; nt < 4; ++nt)
            acc[ar][nt] = (f32x4){0.f, 0.f, 0.f, 0.f};

    // prologue: stage kt=0 into buf 0
    #pragma unroll
    for (int j = 0; j < NSTG; ++j) {
        int idx = tid + j * 256;
        if (idx < TOT) {
            const unsigned short* g = (idx < A_CH) ? WAblk + (size_t)idx * 8
                                                   : XBb + (size_t)(idx - A_CH) * 8;
            GLOAD16(g, smem + idx * 16);
        }
    }
    __syncthreads();

    for (int kt = 0; kt < NKT; ++kt) {
        int cur = kt & 1;
        if (kt + 1 < NKT) {   // stage next tile into other buffer (issued early)
            const unsigned short* wa = WAblk + (size_t)(kt + 1) * A_ELEMS;
            const unsigned short* xb = XBb + (size_t)(kt + 1) * B_TILE;
            char* nb = smem + (cur ^ 1) * TBYTES;
            #pragma unroll
            for (int j = 0; j < NSTG; ++j) {
                int idx = tid + j * 256;
                if (idx < TOT) {
                    const unsigned short* g = (idx < A_CH) ? wa + (size_t)idx * 8
                                                           : xb + (size_t)(idx - A_CH) * 8;
                    GLOAD16(g, nb + idx * 16);
                }
            }
        }
        const char* base = smem + cur * TBYTES;
        f16x8 ah0 = *(const f16x8*)(base + aoff[0][0]);
        f16x8 ah1 = *(const f16x8*)(base + aoff[0][1]);
        f16x8 al0, al1;
        if constexpr (SPLIT) {
            al0 = *(const f16x8*)(base + aoff[1][0]);
            al1 = *(const f16x8*)(base + aoff[1][1]);
        }
        f16x8 bf[4];
        #pragma unroll
        for (int nt = 0; nt < 4; ++nt)
            if (nt < NTW)
                bf[nt] = *(const f16x8*)(base + boff[nt]);
        #pragma unroll
        for (int nt = 0; nt < 4; ++nt) {
            if (nt >= NTW) continue;
            acc[0][nt] = __builtin_amdgcn_mfma_f32_16x16x32_f16(ah0, bf[nt], acc[0][nt], 0, 0, 0);
            if constexpr (SPLIT)
                acc[0][nt] = __builtin_amdgcn_mfma_f32_16x16x32_f16(al0, bf[nt], acc[0][nt], 0, 0, 0);
            acc[1][nt] = __builtin_amdgcn_mfma_f32_16x16x32_f16(ah1, bf[nt], acc[1][nt], 0, 0, 0);
            if constexpr (SPLIT)
                acc[1][nt] = __builtin_amdgcn_mfma_f32_16x16x32_f16(al1, bf[nt], acc[1][nt], 0, 0, 0);
        }
        __syncthreads();   // drains vmcnt -> next buffer ready; cur fully read
    }

    // ---- scan phase: reuse LDS ----
    float* zt = (float*)smem;                      // [64][101] f32 = 25856 B
    #pragma unroll
    for (int ar = 0; ar < 2; ++ar)
        #pragma unroll
        for (int nt = 0; nt < 4; ++nt) {
            if (nt >= NTW) continue;
            int t = wc * 64 + nt * 16 + lm;
            if (t < T) {
                #pragma unroll
                for (int r = 0; r < 4; ++r) {
                    int h = wr * 32 + ar * 16 + lg * 4 + r;
                    zt[h * 101 + t] = acc[ar][nt][r];
                }
            }
        }
    __syncthreads();

    if (tid < 64) {   // 64 LIF chains, one per h row
        float cur2 = 0.f, v = 0.f;
        for (int t = 0; t < T; ++t) {
            cur2 = fmaf(0.75f, cur2, zt[tid * 101 + t]);
            v    = fmaf(0.97f, v, cur2);
            float vpre = v;
            zt[tid * 101 + t] = vpre;
            v = (vpre >= 1.25f) ? 0.f : vpre;   // hard reset
        }
    }
    __syncthreads();

    // ---- global write-out S, V: NONTEMPORAL (never re-read; keep L2 for tiles) ----
    size_t gbase = ((size_t)b * H + h0blk * 64) * T;
    for (int idx = tid; idx < 1600; idx += 256) {
        int h = idx / 25, q = idx - (idx / 25) * 25;
        int t0 = q * 4;
        f32x4 sv, vv;
        #pragma unroll
        for (int i = 0; i < 4; ++i) {
            float vpre = zt[h * 101 + t0 + i];
            vv[i] = vpre;
            sv[i] = (vpre >= 1.25f) ? 1.f : 0.f;
        }
        __builtin_nontemporal_store(sv, (f32x4*)&S[gbase + (size_t)h * 100 + t0]);
        __builtin_nontemporal_store(vv, (f32x4*)&V[gbase + (size_t)h * 100 + t0]);
    }
    // ---- spike image (cached: re-read by same-XCD consumers next dispatch) ----
    {
        unsigned short* dstb = sT + ((size_t)b * NKT1 + h0blk * 2) * B_TILE;
        for (int idx = tid; idx < 896; idx += 256) {
            int sub = idx / 448, c = idx - sub * 448;
            int g = c / 112, r = c - (c / 112) * 112;
            int ch0 = sub * 32 + g * 8;
            u16x8 outv;
            #pragma unroll
            for (int j = 0; j < 8; ++j) {
                bool sp = (r < T) && (zt[(ch0 + j) * 101 + r] >= 1.25f);
                outv[j] = sp ? 0x3C00 : 0;
            }
            *(u16x8*)&dstb[(size_t)idx * 8] = outv;
        }
    }
}

// ------ readout from images: R[l][b][o][t] = sum_h ro[o][h]*s[h][t], MFMA ------
__global__ __launch_bounds__(256) void readout_img(
    const unsigned short* __restrict__ r0img,
    const unsigned short* __restrict__ r1img,
    const unsigned short* __restrict__ s0img,
    const unsigned short* __restrict__ s1img,
    float* __restrict__ R)
{
    __shared__ float red[4][2][7][4][64];      // 57344 B
    const int bid = blockIdx.x;
    const int l = bid >> 6, b = bid & 63;
    const unsigned short* ro = l ? r1img : r0img;
    const unsigned short* im = (l ? s1img : s0img) + (size_t)b * NKT1 * B_TILE;
    const int tid = threadIdx.x, lane = tid & 63, wave = tid >> 6;
    const int lm = lane & 15, lg = lane >> 4;

    f32x4 acc[2][7];
    #pragma unroll
    for (int ar = 0; ar < 2; ++ar)
        #pragma unroll
        for (int nt = 0; nt < 7; ++nt)
            acc[ar][nt] = (f32x4){0.f, 0.f, 0.f, 0.f};

    for (int kt = wave; kt < NKT1; kt += 4) {
        const unsigned short* A  = ro + (size_t)kt * 1024;
        const unsigned short* Bp = im + (size_t)kt * B_TILE;
        f16x8 a[2];
        #pragma unroll
        for (int ar = 0; ar < 2; ++ar) {
            int row = ar * 16 + lm;
            a[ar] = *(const f16x8*)&A[lg * 256 + row * 8];
        }
        #pragma unroll
        for (int nt = 0; nt < 7; ++nt) {
            int row = nt * 16 + lm;
            f16x8 bb = *(const f16x8*)&Bp[lg * 896 + row * 8];
            #pragma unroll
            for (int ar = 0; ar < 2; ++ar)
                acc[ar][nt] = __builtin_amdgcn_mfma_f32_16x16x32_f16(
                    a[ar], bb, acc[ar][nt], 0, 0, 0);
        }
    }
    #pragma unroll
    for (int ar = 0; ar < 2; ++ar)
        #pragma unroll
        for (int nt = 0; nt < 7; ++nt)
            #pragma unroll
            for (int r = 0; r < 4; ++r)
                red[wave][ar][nt][r][lane] = acc[ar][nt][r];
    __syncthreads();

    for (int idx = tid; idx < 3584; idx += 256) {
        int ln = idx & 63;
        int rest = idx >> 6;
        int rg = rest & 3;
        int rest2 = rest >> 2;
        int nt = rest2 % 7, ar = rest2 / 7;
        float s = red[0][ar][nt][rg][ln] + red[1][ar][nt][rg][ln]
                + red[2][ar][nt][rg][ln] + red[3][ar][nt][rg][ln];
        int o = ar * 16 + (ln >> 4) * 4 + rg;
        int t = nt * 16 + (ln & 15);
        if (o < O && t < T)
            R[(((size_t)l * B + b) * O + o) * T + t] = s;
    }
}

// ---------------- standalone readout (fallback path only) ----------------
__global__ __launch_bounds__(128) void readout_kernel(
    const float* __restrict__ ro0, const float* __restrict__ ro1,
    const float* __restrict__ Sall, float* __restrict__ R)
{
    int bid = blockIdx.x;
    int l = bid / (B * O);
    int rem = bid - l * (B * O);
    int b = rem / O, o = rem - (rem / O) * O;
    int t = threadIdx.x;
    if (t >= T) return;
    const float* ro = (l == 0 ? ro0 : ro1) + (size_t)o * H;
    const float* s  = Sall + (size_t)l * B * H * T + (size_t)b * H * T + t;
    float acc = 0.f;
    #pragma unroll 8
    for (int h = 0; h < H; ++h)
        acc = fmaf(ro[h], s[(size_t)h * T], acc);
    R[(size_t)l * B * O * T + (size_t)b * O * T + (size_t)o * T + t] = acc;
}

// ---------------- fallback fp32 path (round-1, known correct) ----------------
__global__ __launch_bounds__(256) void gemm_scan_f32(
    const float* __restrict__ W, const float* __restrict__ X,
    int K, long xbs, float* __restrict__ S, float* __restrict__ V)
{
    __shared__ float fxs[16][112];
    __shared__ float fwl[64][16];
    __shared__ float fzt[64][101];
    __shared__ float fst[64][101];
    const int tid = threadIdx.x;
    const int tx = tid & 15, ty = tid >> 4;
    const int b = blockIdx.y, h0 = blockIdx.x * 64;
    const float* Xb = X + (long)b * xbs;
    float acc[4][7];
    #pragma unroll
    for (int k = 0; k < 4; ++k)
        #pragma unroll
        for (int j = 0; j < 7; ++j) acc[k][j] = 0.f;
    for (int cc = 0; cc < K; cc += 16) {
        for (int idx = tid; idx < 16 * 112; idx += 256) {
            int c = idx / 112, t = idx - c * 112;
            float v = 0.f;
            if (t < T && cc + c < K) v = Xb[(long)(cc + c) * T + t];
            fxs[c][t] = v;
        }
        for (int idx = tid; idx < 64 * 16; idx += 256) {
            int h = idx >> 4, c = idx & 15;
            float v = 0.f;
            if (cc + c < K) v = W[(long)(h0 + h) * K + cc + c];
            fwl[h][c] = v;
        }
        __syncthreads();
        #pragma unroll
        for (int c = 0; c < 16; ++c) {
            float wv[4], xv[7];
            #pragma unroll
            for (int k = 0; k < 4; ++k) wv[k] = fwl[ty + 16 * k][c];
            #pragma unroll
            for (int j = 0; j < 7; ++j) xv[j] = fxs[c][tx + 16 * j];
            #pragma unroll
            for (int k = 0; k < 4; ++k)
                #pragma unroll
                for (int j = 0; j < 7; ++j)
                    acc[k][j] = fmaf(wv[k], xv[j], acc[k][j]);
        }
        __syncthreads();
    }
    #pragma unroll
    for (int k = 0; k < 4; ++k)
        #pragma unroll
        for (int j = 0; j < 7; ++j) {
            int t = tx + 16 * j;
            if (t < T) fzt[ty + 16 * k][t] = acc[k][j];
        }
    __syncthreads();
    if (tid < 64) {
        float cur = 0.f, v = 0.f;
        for (int t = 0; t < T; ++t) {
            cur = fmaf(0.75f, cur, fzt[tid][t]);
            v = fmaf(0.97f, v, cur);
            float s = (v >= 1.25f) ? 1.f : 0.f;
            fst[tid][t] = s;
            fzt[tid][t] = v;
            v *= (1.f - s);
        }
    }
    __syncthreads();
    long base = (long)b * H * T + (long)h0 * T;
    for (int idx = tid; idx < 64 * T; idx += 256) {
        int h = idx / T, t = idx - (idx / T) * T;
        S[base + idx] = fst[h][t];
        V[base + idx] = fzt[h][t];
    }
}

extern "C" void kernel_launch(void* const* d_in, const int* in_sizes, int n_in,
                              void* d_out, int out_size, void* d_ws, size_t ws_size,
                              hipStream_t stream) {
    const float* spike = (const float*)d_in[0];
    const float* w0    = (const float*)d_in[1];
    const float* w1    = (const float*)d_in[2];
    const float* ro0   = (const float*)d_in[3];
    const float* ro1   = (const float*)d_in[4];

    float* out = (float*)d_out;
    float* S = out;
    float* R = out + 2L * B * H * T;
    float* V = out + 2L * B * H * T + 2L * B * O * T;

    const size_t nW0 = (size_t)32 * NKT0 * A_TILE_S;
    const size_t nW1 = (size_t)32 * NKT1 * A_TILE_H;   // hi-only
    const size_t nX0 = (size_t)B * NKT0 * B_TILE;
    const size_t nS  = (size_t)B * NKT1 * B_TILE;
    const size_t nRO = (size_t)NKT1 * 1024;
    const size_t need = (nW0 + nW1 + nX0 + 2 * nS + 2 * nRO) * sizeof(unsigned short);

    if (ws_size >= need) {
        unsigned short* p = (unsigned short*)d_ws;
        unsigned short* w0img = p; p += nW0;
        unsigned short* w1img = p; p += nW1;
        unsigned short* x0img = p; p += nX0;
        unsigned short* s0img = p; p += nS;
        unsigned short* s1img = p; p += nS;
        unsigned short* r0img = p; p += nRO;
        unsigned short* r1img = p; p += nRO;

        prepass_all<<<PRE_BLKS, 256, 0, stream>>>(spike, w0, w1, ro0, ro1,
                                                  w0img, w1img, x0img,
                                                  r0img, r1img);

        gemm_scan_t<1><<<2048, 256, 0, stream>>>(w0img, x0img, NKT0, S, V, s0img);
        gemm_scan_t<0><<<2048, 256, 0, stream>>>(w1img, s0img, NKT1,
                                                 S + (size_t)B * H * T,
                                                 V + (size_t)B * H * T, s1img);
        readout_img<<<128, 256, 0, stream>>>(r0img, r1img, s0img, s1img, R);
    } else {
        dim3 grid(H / 64, B);
        gemm_scan_f32<<<grid, 256, 0, stream>>>(w0, spike, I, (long)I * T, S, V);
        gemm_scan_f32<<<grid, 256, 0, stream>>>(w1, S, H, (long)H * T,
                                                S + (long)B * H * T, V + (long)B * H * T);
        readout_kernel<<<2 * B * O, 128, 0, stream>>>(ro0, ro1, S, R);
    }
}

// Round 18
// 169.407 us; speedup vs baseline: 1.3666x; 1.0844x over previous
//
#include <hip/hip_runtime.h>

using f16x8 = __attribute__((ext_vector_type(8))) _Float16;
using f32x4 = __attribute__((ext_vector_type(4))) float;
using u16x8 = __attribute__((ext_vector_type(8))) unsigned short;

constexpr int B = 64, I = 700, H = 2048, O = 20, T = 100;
constexpr int NKT0 = 22;        // K-tiles layer 0 (704 = 22*32)
constexpr int NKT1 = 64;        // K-tiles layer 1 (2048 = 64*32)
// tile layouts (k-group-major, chunk-linear):
//   A hi-only tile: [4 g][64 rows][8 f16]       = 256 chunks
//   B tile        : [4 g][112 rows (t)][8 f16]  = 448 chunks
constexpr int A_TILE_H = 2048;  // ushorts (hi-only)
constexpr int B_TILE = 3584;    // ushorts

// merged prepass block ranges
constexpr int PW0_BLKS = (32 * NKT0 * 256) / 256;   // 704  (hi-only tiles)
constexpr int PW1_BLKS = (32 * NKT1 * 256) / 256;   // 2048 (hi-only tiles)
constexpr int PX_BLKS  = NKT0 * B;                  // 1408
constexpr int PRO_BLKS = NKT1;                      // 64 (both layers per block)
constexpr int PRE_BLKS = PW0_BLKS + PW1_BLKS + PX_BLKS + PRO_BLKS;

#define GLOAD16(gp, lp) __builtin_amdgcn_global_load_lds( \
    (const __attribute__((address_space(1))) unsigned int*)(const void*)(gp), \
    (__attribute__((address_space(3))) unsigned int*)(void*)(lp), 16, 0, 0)

// ---------------- merged pre-pass bodies ----------------
__device__ inline void conv_w_hi_body(const float* __restrict__ w, int K, int NKT,
                                      int idx, unsigned short* __restrict__ dst)
{
    int c = idx & 255, img = idx >> 8;
    int h0blk = img / NKT, kt = img - h0blk * NKT;
    int g = c >> 6, row = c & 63;
    int kbase = kt * 32 + g * 8;
    const float* wrow = w + (size_t)(h0blk * 64 + row) * K;
    u16x8 outv;
    #pragma unroll
    for (int j = 0; j < 8; ++j) {
        int k = kbase + j;
        float f = (k < K) ? wrow[k] : 0.f;
        _Float16 hv = (_Float16)f;
        outv[j] = *(unsigned short*)&hv;
    }
    *(u16x8*)&dst[(size_t)idx * 8] = outv;
}

__global__ __launch_bounds__(256) void prepass_all(
    const float* __restrict__ spike,
    const float* __restrict__ w0, const float* __restrict__ w1,
    const float* __restrict__ ro0, const float* __restrict__ ro1,
    unsigned short* __restrict__ w0img, unsigned short* __restrict__ w1img,
    unsigned short* __restrict__ x0img,
    unsigned short* __restrict__ r0img, unsigned short* __restrict__ r1img)
{
    __shared__ float xs[32][101];
    int bid = blockIdx.x;
    if (bid < PW0_BLKS) {
        conv_w_hi_body(w0, I, NKT0, bid * 256 + threadIdx.x, w0img);
    } else if (bid < PW0_BLKS + PW1_BLKS) {
        conv_w_hi_body(w1, H, NKT1, (bid - PW0_BLKS) * 256 + threadIdx.x, w1img);
    } else if (bid < PW0_BLKS + PW1_BLKS + PX_BLKS) {
        // X transpose: fp32 [B][I][T] -> B-tiles
        int q = bid - (PW0_BLKS + PW1_BLKS);
        int kt = q % NKT0, b = q / NKT0;
        int c0 = kt * 32;
        const float* Xb = spike + (size_t)b * I * T;
        for (int idx = threadIdx.x; idx < 32 * T; idx += 256) {
            int ci = idx / T, t = idx - (idx / T) * T;
            xs[ci][t] = (c0 + ci < I) ? Xb[(size_t)(c0 + ci) * T + t] : 0.f;
        }
        __syncthreads();
        unsigned short* dst = x0img + ((size_t)b * NKT0 + kt) * B_TILE;
        for (int idx = threadIdx.x; idx < 448; idx += 256) {
            int g = idx / 112, r = idx - (idx / 112) * 112;
            u16x8 outv;
            #pragma unroll
            for (int j = 0; j < 8; ++j) {
                float f = (r < T) ? xs[g * 8 + j][r] : 0.f;
                _Float16 h = (_Float16)f;
                outv[j] = *(unsigned short*)&h;
            }
            *(u16x8*)&dst[(size_t)idx * 8] = outv;
        }
    } else {
        // ro conversion, both layers: [O][H] -> per-kt32 A-tiles
        int kt = bid - (PW0_BLKS + PW1_BLKS + PX_BLKS);
        int l = threadIdx.x >> 7, c = threadIdx.x & 127;
        const float* ro = l ? ro1 : ro0;
        unsigned short* dst = l ? r1img : r0img;
        int g = c >> 5, row = c & 31;
        int k0 = kt * 32 + g * 8;
        u16x8 outv;
        #pragma unroll
        for (int j = 0; j < 8; ++j) {
            float f = (row < O) ? ro[(size_t)row * H + k0 + j] : 0.f;
            _Float16 hv = (_Float16)f;
            outv[j] = *(unsigned short*)&hv;
        }
        *(u16x8*)&dst[((size_t)kt * 128 + c) * 8] = outv;
    }
}

// ------ fused MFMA GEMM (BK=32, 2-phase gload_lds, hi-only f16) + CUBA scan ---
__global__ __launch_bounds__(256, 4) void gemm_scan_hi(
    const unsigned short* __restrict__ WA,   // [32][NKT][A_TILE_H]
    const unsigned short* __restrict__ XB,   // [64][NKT][B_TILE]
    int NKT,
    float* __restrict__ S, float* __restrict__ V,
    unsigned short* __restrict__ sT)
{
    constexpr int A_CH = 256;                  // A chunks per tile
    constexpr int TOT  = A_CH + 448;           // 704 chunks per tile
    constexpr int TBYTES = TOT * 16;           // 11264 B per buffer

    __shared__ __align__(16) char smem[2 * 15360];   // scan overlay needs 25856
    const int tid = threadIdx.x;
    const int lane = tid & 63, wave = tid >> 6;
    const int lm = lane & 15, lg = lane >> 4;
    const int wr = wave >> 1, wc = wave & 1;
    const int NTW = 4 - wc;

    // XCD-aware decode: blocks with same b land on same XCD
    int orig = blockIdx.x;
    int xcd = orig & 7, slot = orig >> 3;
    int b = xcd * 8 + (slot & 7);
    int h0blk = slot >> 3;

    const unsigned short* WAblk = WA + (size_t)h0blk * NKT * A_TILE_H;
    const unsigned short* XBb   = XB + (size_t)b * NKT * B_TILE;

    // fragment byte offsets within one buffer (kt-invariant)
    int aoff[2], boff[4];
    #pragma unroll
    for (int ar = 0; ar < 2; ++ar) {
        int row = wr * 32 + ar * 16 + lm;
        aoff[ar] = lg * 1024 + row * 16;
    }
    #pragma unroll
    for (int nt = 0; nt < 4; ++nt) {
        int row = wc * 64 + nt * 16 + lm;
        boff[nt] = A_CH * 16 + lg * 1792 + row * 16;
    }

    f32x4 acc[2][4];
    #pragma unroll
    for (int ar = 0; ar < 2; ++ar)
        #pragma unroll
        for (int nt = 0; nt < 4; ++nt)
            acc[ar][nt] = (f32x4){0.f, 0.f, 0.f, 0.f};

    // prologue: stage kt=0 into buf 0
    #pragma unroll
    for (int j = 0; j < 3; ++j) {
        int idx = tid + j * 256;
        if (idx < TOT) {
            const unsigned short* g = (idx < A_CH) ? WAblk + (size_t)idx * 8
                                                   : XBb + (size_t)(idx - A_CH) * 8;
            GLOAD16(g, smem + idx * 16);
        }
    }
    __syncthreads();

    for (int kt = 0; kt < NKT; ++kt) {
        int cur = kt & 1;
        if (kt + 1 < NKT) {   // stage next tile into other buffer (issued early)
            const unsigned short* wa = WAblk + (size_t)(kt + 1) * A_TILE_H;
            const unsigned short* xb = XBb + (size_t)(kt + 1) * B_TILE;
            char* nb = smem + (cur ^ 1) * TBYTES;
            #pragma unroll
            for (int j = 0; j < 3; ++j) {
                int idx = tid + j * 256;
                if (idx < TOT) {
                    const unsigned short* g = (idx < A_CH) ? wa + (size_t)idx * 8
                                                           : xb + (size_t)(idx - A_CH) * 8;
                    GLOAD16(g, nb + idx * 16);
                }
            }
        }
        const char* base = smem + cur * TBYTES;
        f16x8 ah0 = *(const f16x8*)(base + aoff[0]);
        f16x8 ah1 = *(const f16x8*)(base + aoff[1]);
        f16x8 bf[4];
        #pragma unroll
        for (int nt = 0; nt < 4; ++nt)
            if (nt < NTW)
                bf[nt] = *(const f16x8*)(base + boff[nt]);
        #pragma unroll
        for (int nt = 0; nt < 4; ++nt) {
            if (nt >= NTW) continue;
            acc[0][nt] = __builtin_amdgcn_mfma_f32_16x16x32_f16(ah0, bf[nt], acc[0][nt], 0, 0, 0);
            acc[1][nt] = __builtin_amdgcn_mfma_f32_16x16x32_f16(ah1, bf[nt], acc[1][nt], 0, 0, 0);
        }
        __syncthreads();   // drains vmcnt -> next buffer ready; cur fully read
    }

    // ---- scan phase: reuse LDS ----
    float* zt = (float*)smem;                      // [64][101] f32 = 25856 B
    #pragma unroll
    for (int ar = 0; ar < 2; ++ar)
        #pragma unroll
        for (int nt = 0; nt < 4; ++nt) {
            if (nt >= NTW) continue;
            int t = wc * 64 + nt * 16 + lm;
            if (t < T) {
                #pragma unroll
                for (int r = 0; r < 4; ++r) {
                    int h = wr * 32 + ar * 16 + lg * 4 + r;
                    zt[h * 101 + t] = acc[ar][nt][r];
                }
            }
        }
    __syncthreads();

    if (tid < 64) {   // 64 LIF chains, one per h row
        float cur2 = 0.f, v = 0.f;
        for (int t = 0; t < T; ++t) {
            cur2 = fmaf(0.75f, cur2, zt[tid * 101 + t]);
            v    = fmaf(0.97f, v, cur2);
            float vpre = v;
            zt[tid * 101 + t] = vpre;
            v = (vpre >= 1.25f) ? 0.f : vpre;   // hard reset
        }
    }
    __syncthreads();

    // ---- global write-out S, V: NONTEMPORAL (never re-read; keep L2 for tiles) ----
    size_t gbase = ((size_t)b * H + h0blk * 64) * T;
    for (int idx = tid; idx < 1600; idx += 256) {
        int h = idx / 25, q = idx - (idx / 25) * 25;
        int t0 = q * 4;
        f32x4 sv, vv;
        #pragma unroll
        for (int i = 0; i < 4; ++i) {
            float vpre = zt[h * 101 + t0 + i];
            vv[i] = vpre;
            sv[i] = (vpre >= 1.25f) ? 1.f : 0.f;
        }
        __builtin_nontemporal_store(sv, (f32x4*)&S[gbase + (size_t)h * 100 + t0]);
        __builtin_nontemporal_store(vv, (f32x4*)&V[gbase + (size_t)h * 100 + t0]);
    }
    // ---- spike image (cached: re-read by same-XCD consumers next dispatch) ----
    {
        unsigned short* dstb = sT + ((size_t)b * NKT1 + h0blk * 2) * B_TILE;
        for (int idx = tid; idx < 896; idx += 256) {
            int sub = idx / 448, c = idx - sub * 448;
            int g = c / 112, r = c - (c / 112) * 112;
            int ch0 = sub * 32 + g * 8;
            u16x8 outv;
            #pragma unroll
            for (int j = 0; j < 8; ++j) {
                bool sp = (r < T) && (zt[(ch0 + j) * 101 + r] >= 1.25f);
                outv[j] = sp ? 0x3C00 : 0;
            }
            *(u16x8*)&dstb[(size_t)idx * 8] = outv;
        }
    }
}

// ------ readout from images: R[l][b][o][t] = sum_h ro[o][h]*s[h][t], MFMA ------
__global__ __launch_bounds__(256) void readout_img(
    const unsigned short* __restrict__ r0img,
    const unsigned short* __restrict__ r1img,
    const unsigned short* __restrict__ s0img,
    const unsigned short* __restrict__ s1img,
    float* __restrict__ R)
{
    __shared__ float red[4][2][7][4][64];      // 57344 B
    const int bid = blockIdx.x;
    const int l = bid >> 6, b = bid & 63;
    const unsigned short* ro = l ? r1img : r0img;
    const unsigned short* im = (l ? s1img : s0img) + (size_t)b * NKT1 * B_TILE;
    const int tid = threadIdx.x, lane = tid & 63, wave = tid >> 6;
    const int lm = lane & 15, lg = lane >> 4;

    f32x4 acc[2][7];
    #pragma unroll
    for (int ar = 0; ar < 2; ++ar)
        #pragma unroll
        for (int nt = 0; nt < 7; ++nt)
            acc[ar][nt] = (f32x4){0.f, 0.f, 0.f, 0.f};

    for (int kt = wave; kt < NKT1; kt += 4) {
        const unsigned short* A  = ro + (size_t)kt * 1024;
        const unsigned short* Bp = im + (size_t)kt * B_TILE;
        f16x8 a[2];
        #pragma unroll
        for (int ar = 0; ar < 2; ++ar) {
            int row = ar * 16 + lm;
            a[ar] = *(const f16x8*)&A[lg * 256 + row * 8];
        }
        #pragma unroll
        for (int nt = 0; nt < 7; ++nt) {
            int row = nt * 16 + lm;
            f16x8 bb = *(const f16x8*)&Bp[lg * 896 + row * 8];
            #pragma unroll
            for (int ar = 0; ar < 2; ++ar)
                acc[ar][nt] = __builtin_amdgcn_mfma_f32_16x16x32_f16(
                    a[ar], bb, acc[ar][nt], 0, 0, 0);
        }
    }
    #pragma unroll
    for (int ar = 0; ar < 2; ++ar)
        #pragma unroll
        for (int nt = 0; nt < 7; ++nt)
            #pragma unroll
            for (int r = 0; r < 4; ++r)
                red[wave][ar][nt][r][lane] = acc[ar][nt][r];
    __syncthreads();

    for (int idx = tid; idx < 3584; idx += 256) {
        int ln = idx & 63;
        int rest = idx >> 6;
        int rg = rest & 3;
        int rest2 = rest >> 2;
        int nt = rest2 % 7, ar = rest2 / 7;
        float s = red[0][ar][nt][rg][ln] + red[1][ar][nt][rg][ln]
                + red[2][ar][nt][rg][ln] + red[3][ar][nt][rg][ln];
        int o = ar * 16 + (ln >> 4) * 4 + rg;
        int t = nt * 16 + (ln & 15);
        if (o < O && t < T)
            R[(((size_t)l * B + b) * O + o) * T + t] = s;
    }
}

// ---------------- standalone readout (fallback path only) ----------------
__global__ __launch_bounds__(128) void readout_kernel(
    const float* __restrict__ ro0, const float* __restrict__ ro1,
    const float* __restrict__ Sall, float* __restrict__ R)
{
    int bid = blockIdx.x;
    int l = bid / (B * O);
    int rem = bid - l * (B * O);
    int b = rem / O, o = rem - (rem / O) * O;
    int t = threadIdx.x;
    if (t >= T) return;
    const float* ro = (l == 0 ? ro0 : ro1) + (size_t)o * H;
    const float* s  = Sall + (size_t)l * B * H * T + (size_t)b * H * T + t;
    float acc = 0.f;
    #pragma unroll 8
    for (int h = 0; h < H; ++h)
        acc = fmaf(ro[h], s[(size_t)h * T], acc);
    R[(size_t)l * B * O * T + (size_t)b * O * T + (size_t)o * T + t] = acc;
}

// ---------------- fallback fp32 path (round-1, known correct) ----------------
__global__ __launch_bounds__(256) void gemm_scan_f32(
    const float* __restrict__ W, const float* __restrict__ X,
    int K, long xbs, float* __restrict__ S, float* __restrict__ V)
{
    __shared__ float fxs[16][112];
    __shared__ float fwl[64][16];
    __shared__ float fzt[64][101];
    __shared__ float fst[64][101];
    const int tid = threadIdx.x;
    const int tx = tid & 15, ty = tid >> 4;
    const int b = blockIdx.y, h0 = blockIdx.x * 64;
    const float* Xb = X + (long)b * xbs;
    float acc[4][7];
    #pragma unroll
    for (int k = 0; k < 4; ++k)
        #pragma unroll
        for (int j = 0; j < 7; ++j) acc[k][j] = 0.f;
    for (int cc = 0; cc < K; cc += 16) {
        for (int idx = tid; idx < 16 * 112; idx += 256) {
            int c = idx / 112, t = idx - c * 112;
            float v = 0.f;
            if (t < T && cc + c < K) v = Xb[(long)(cc + c) * T + t];
            fxs[c][t] = v;
        }
        for (int idx = tid; idx < 64 * 16; idx += 256) {
            int h = idx >> 4, c = idx & 15;
            float v = 0.f;
            if (cc + c < K) v = W[(long)(h0 + h) * K + cc + c];
            fwl[h][c] = v;
        }
        __syncthreads();
        #pragma unroll
        for (int c = 0; c < 16; ++c) {
            float wv[4], xv[7];
            #pragma unroll
            for (int k = 0; k < 4; ++k) wv[k] = fwl[ty + 16 * k][c];
            #pragma unroll
            for (int j = 0; j < 7; ++j) xv[j] = fxs[c][tx + 16 * j];
            #pragma unroll
            for (int k = 0; k < 4; ++k)
                #pragma unroll
                for (int j = 0; j < 7; ++j)
                    acc[k][j] = fmaf(wv[k], xv[j], acc[k][j]);
        }
        __syncthreads();
    }
    #pragma unroll
    for (int k = 0; k < 4; ++k)
        #pragma unroll
        for (int j = 0; j < 7; ++j) {
            int t = tx + 16 * j;
            if (t < T) fzt[ty + 16 * k][t] = acc[k][j];
        }
    __syncthreads();
    if (tid < 64) {
        float cur = 0.f, v = 0.f;
        for (int t = 0; t < T; ++t) {
            cur = fmaf(0.75f, cur, fzt[tid][t]);
            v = fmaf(0.97f, v, cur);
            float s = (v >= 1.25f) ? 1.f : 0.f;
            fst[tid][t] = s;
            fzt[tid][t] = v;
            v *= (1.f - s);
        }
    }
    __syncthreads();
    long base = (long)b * H * T + (long)h0 * T;
    for (int idx = tid; idx < 64 * T; idx += 256) {
        int h = idx / T, t = idx - (idx / T) * T;
        S[base + idx] = fst[h][t];
        V[base + idx] = fzt[h][t];
    }
}

extern "C" void kernel_launch(void* const* d_in, const int* in_sizes, int n_in,
                              void* d_out, int out_size, void* d_ws, size_t ws_size,
                              hipStream_t stream) {
    const float* spike = (const float*)d_in[0];
    const float* w0    = (const float*)d_in[1];
    const float* w1    = (const float*)d_in[2];
    const float* ro0   = (const float*)d_in[3];
    const float* ro1   = (const float*)d_in[4];

    float* out = (float*)d_out;
    float* S = out;
    float* R = out + 2L * B * H * T;
    float* V = out + 2L * B * H * T + 2L * B * O * T;

    const size_t nW0 = (size_t)32 * NKT0 * A_TILE_H;   // hi-only
    const size_t nW1 = (size_t)32 * NKT1 * A_TILE_H;   // hi-only
    const size_t nX0 = (size_t)B * NKT0 * B_TILE;
    const size_t nS  = (size_t)B * NKT1 * B_TILE;
    const size_t nRO = (size_t)NKT1 * 1024;
    const size_t need = (nW0 + nW1 + nX0 + 2 * nS + 2 * nRO) * sizeof(unsigned short);

    if (ws_size >= need) {
        unsigned short* p = (unsigned short*)d_ws;
        unsigned short* w0img = p; p += nW0;
        unsigned short* w1img = p; p += nW1;
        unsigned short* x0img = p; p += nX0;
        unsigned short* s0img = p; p += nS;
        unsigned short* s1img = p; p += nS;
        unsigned short* r0img = p; p += nRO;
        unsigned short* r1img = p; p += nRO;

        prepass_all<<<PRE_BLKS, 256, 0, stream>>>(spike, w0, w1, ro0, ro1,
                                                  w0img, w1img, x0img,
                                                  r0img, r1img);

        gemm_scan_hi<<<2048, 256, 0, stream>>>(w0img, x0img, NKT0, S, V, s0img);
        gemm_scan_hi<<<2048, 256, 0, stream>>>(w1img, s0img, NKT1,
                                               S + (size_t)B * H * T,
                                               V + (size_t)B * H * T, s1img);
        readout_img<<<128, 256, 0, stream>>>(r0img, r1img, s0img, s1img, R);
    } else {
        dim3 grid(H / 64, B);
        gemm_scan_f32<<<grid, 256, 0, stream>>>(w0, spike, I, (long)I * T, S, V);
        gemm_scan_f32<<<grid, 256, 0, stream>>>(w1, S, H, (long)H * T,
                                                S + (long)B * H * T, V + (long)B * H * T);
        readout_kernel<<<2 * B * O, 128, 0, stream>>>(ro0, ro1, S, R);
    }
}